// Round 3
// baseline (105.617 us; speedup 1.0000x reference)
//
#include <hip/hip_runtime.h>
#include <cstdint>
#include <cstddef>

#define N_NODES 4096
#define IN_DIM  512
#define HEADS   8
#define HID     64
#define OUTF    (HEADS * HID)   // 512
#define SLOPE   0.2f
#define MAXD    256             // degree ~ Binom(4096,0.01): mean 41, P(>255) ~ 0

typedef __bf16 bf16_t;
typedef __attribute__((ext_vector_type(8))) __bf16 bf16x8;
typedef __attribute__((ext_vector_type(4))) float    f32x4;

#define GLD16(gp, lp)                                                                  \
    __builtin_amdgcn_global_load_lds((const __attribute__((address_space(1))) void*)(gp), \
                                     (__attribute__((address_space(3))) void*)(lp), 16, 0, 0)

__device__ __forceinline__ unsigned short to_bf16_u(float x) {
    uint32_t u = __builtin_bit_cast(uint32_t, x);
    u += 0x7fffu + ((u >> 16) & 1u);
    return (unsigned short)(u >> 16);
}
__device__ __forceinline__ float bfbits_to_f(unsigned short b) {
    uint32_t u = ((uint32_t)b) << 16;
    return __builtin_bit_cast(float, u);
}

// ---------------- pack adj (int32) -> bitmask, 1 bit/col ----------------
// thread t covers ints [16t,16t+16) -> one u16 of the row bitmask.
__global__ __launch_bounds__(256) void pack_adj(const int* __restrict__ adj,
                                                unsigned short* __restrict__ bm16) {
    const int t = blockIdx.x * 256 + threadIdx.x;          // 0 .. 1048575
    const int4* src = (const int4*)adj + (size_t)t * 4;
    const int4 v0 = src[0], v1 = src[1], v2 = src[2], v3 = src[3];
    uint32_t b = 0;
    b |= (v0.x != 0) ? 1u << 0 : 0;  b |= (v0.y != 0) ? 1u << 1 : 0;
    b |= (v0.z != 0) ? 1u << 2 : 0;  b |= (v0.w != 0) ? 1u << 3 : 0;
    b |= (v1.x != 0) ? 1u << 4 : 0;  b |= (v1.y != 0) ? 1u << 5 : 0;
    b |= (v1.z != 0) ? 1u << 6 : 0;  b |= (v1.w != 0) ? 1u << 7 : 0;
    b |= (v2.x != 0) ? 1u << 8 : 0;  b |= (v2.y != 0) ? 1u << 9 : 0;
    b |= (v2.z != 0) ? 1u << 10 : 0; b |= (v2.w != 0) ? 1u << 11 : 0;
    b |= (v3.x != 0) ? 1u << 12 : 0; b |= (v3.y != 0) ? 1u << 13 : 0;
    b |= (v3.z != 0) ? 1u << 14 : 0; b |= (v3.w != 0) ? 1u << 15 : 0;
    bm16[t] = (unsigned short)b;
}

// ---------------- h (f32) -> h_hi, h_lo (bf16) ----------------
__global__ __launch_bounds__(256) void conv_h(const float* __restrict__ h,
                                              unsigned short* __restrict__ hhi,
                                              unsigned short* __restrict__ hlo) {
    const int t = blockIdx.x * 256 + threadIdx.x;          // 0 .. 524287
    const float4 v = ((const float4*)h)[t];
    ushort4 hi, lo;
    hi.x = to_bf16_u(v.x); lo.x = to_bf16_u(v.x - bfbits_to_f(hi.x));
    hi.y = to_bf16_u(v.y); lo.y = to_bf16_u(v.y - bfbits_to_f(hi.y));
    hi.z = to_bf16_u(v.z); lo.z = to_bf16_u(v.z - bfbits_to_f(hi.z));
    hi.w = to_bf16_u(v.w); lo.w = to_bf16_u(v.w - bfbits_to_f(hi.w));
    ((ushort4*)hhi)[t] = hi;
    ((ushort4*)hlo)[t] = lo;
}

// ---------------- W (f32 [k][c]) -> W_hiT, W_loT (bf16 [c][k]) ----------------
__global__ __launch_bounds__(256) void conv_wT(const float* __restrict__ W,
                                               unsigned short* __restrict__ whiT,
                                               unsigned short* __restrict__ wloT) {
    __shared__ unsigned short shi[64][68];
    __shared__ unsigned short slo[64][68];
    const int tid = threadIdx.x;
    const int kt = blockIdx.y * 64;    // k-tile base
    const int ct = blockIdx.x * 64;    // col-tile base
#pragma unroll
    for (int rr = 0; rr < 4; ++rr) {
        const int lk = rr * 16 + (tid >> 4);
        const int lc = (tid & 15) * 4;
        const float4 v = *(const float4*)&W[(size_t)(kt + lk) * OUTF + ct + lc];
        shi[lk][lc + 0] = to_bf16_u(v.x); slo[lk][lc + 0] = to_bf16_u(v.x - bfbits_to_f(shi[lk][lc + 0]));
        shi[lk][lc + 1] = to_bf16_u(v.y); slo[lk][lc + 1] = to_bf16_u(v.y - bfbits_to_f(shi[lk][lc + 1]));
        shi[lk][lc + 2] = to_bf16_u(v.z); slo[lk][lc + 2] = to_bf16_u(v.z - bfbits_to_f(shi[lk][lc + 2]));
        shi[lk][lc + 3] = to_bf16_u(v.w); slo[lk][lc + 3] = to_bf16_u(v.w - bfbits_to_f(shi[lk][lc + 3]));
    }
    __syncthreads();
#pragma unroll
    for (int rr = 0; rr < 4; ++rr) {
        const int lc = rr * 16 + (tid >> 4);
        const int lk = (tid & 15) * 4;
        ushort4 hv, lv;
        hv.x = shi[lk + 0][lc]; hv.y = shi[lk + 1][lc]; hv.z = shi[lk + 2][lc]; hv.w = shi[lk + 3][lc];
        lv.x = slo[lk + 0][lc]; lv.y = slo[lk + 1][lc]; lv.z = slo[lk + 2][lc]; lv.w = slo[lk + 3][lc];
        *(ushort4*)&whiT[(size_t)(ct + lc) * IN_DIM + kt + lk] = hv;
        *(ushort4*)&wloT[(size_t)(ct + lc) * IN_DIM + kt + lk] = lv;
    }
}

// ---------------- MFMA GEMM: g = h_hi@W_hi + h_hi@W_lo + h_lo@W_hi ----------------
// 128x128 tile, BK=32, 4 waves (2x2), wave tile 64x64 (4x4 frags of 16x16x32).
// LDS layout [row][k] for A, [col][k] for B (W pre-transposed), chunk-swizzled
// c ^= (row>>1)&3 on BOTH stage-source and frag-read (conflict-free ds_read_b128).
__global__ __launch_bounds__(256) void gemm_mfma(const bf16_t* __restrict__ Ahi,
                                                 const bf16_t* __restrict__ Alo,
                                                 const bf16_t* __restrict__ BhiT,
                                                 const bf16_t* __restrict__ BloT,
                                                 float* __restrict__ C) {
    __shared__ bf16_t As[2][128 * 32];   // 8KB each
    __shared__ bf16_t Bs[2][128 * 32];   // 8KB each

    const int tid  = threadIdx.x;
    const int wid  = tid >> 6;
    const int lane = tid & 63;
    const int i0 = blockIdx.y * 128;
    const int j0 = blockIdx.x * 128;

    // staging addresses (elements): thread t -> tile row r=t>>2, chunk c=t&3,
    // fetch global chunk c ^ ((r>>1)&3); LDS dest is linear t*16B.
    const int r    = tid >> 2;
    const int swz  = (tid & 3) ^ ((r >> 1) & 3);
    const size_t aoff0 = (size_t)(i0 + r) * IN_DIM + swz * 8;
    const size_t aoff1 = aoff0 + (size_t)64 * IN_DIM;
    const size_t boff0 = (size_t)(j0 + r) * IN_DIM + swz * 8;
    const size_t boff1 = boff0 + (size_t)64 * IN_DIM;

    // fragment read offsets (elements) within a 128x32 LDS tile
    const int wm = wid >> 1, wn = wid & 1;
    const int kq = lane >> 4, l15 = lane & 15;
    int aro[4], bro[4];
#pragma unroll
    for (int m = 0; m < 4; ++m) {
        const int row = wm * 64 + m * 16 + l15;
        aro[m] = row * 32 + ((kq ^ ((row >> 1) & 3)) * 8);
    }
#pragma unroll
    for (int n = 0; n < 4; ++n) {
        const int col = wn * 64 + n * 16 + l15;
        bro[n] = col * 32 + ((kq ^ ((col >> 1) & 3)) * 8);
    }

    f32x4 acc[4][4] = {};

    auto stage = [&](int buf, int it) {
        const int seg = it >> 4;
        const int k0  = (it & 15) << 5;
        const bf16_t* Asrc = (seg == 2) ? Alo : Ahi;
        const bf16_t* Bsrc = (seg == 1) ? BloT : BhiT;
        GLD16(Asrc + aoff0 + k0, &As[buf][wid * 512]);
        GLD16(Asrc + aoff1 + k0, &As[buf][2048 + wid * 512]);
        GLD16(Bsrc + boff0 + k0, &Bs[buf][wid * 512]);
        GLD16(Bsrc + boff1 + k0, &Bs[buf][2048 + wid * 512]);
    };

    stage(0, 0);
    for (int it = 0; it < 48; ++it) {
        const int cur = it & 1;
        if (it < 47) {
            stage(cur ^ 1, it + 1);
            asm volatile("s_waitcnt vmcnt(4)" ::: "memory");   // wait cur buf (4 older loads)
        } else {
            asm volatile("s_waitcnt vmcnt(0)" ::: "memory");
        }
        __builtin_amdgcn_s_barrier();
        asm volatile("" ::: "memory");

        bf16x8 af[4], bfr[4];
#pragma unroll
        for (int m = 0; m < 4; ++m) af[m] = *(const bf16x8*)&As[cur][aro[m]];
#pragma unroll
        for (int n = 0; n < 4; ++n) bfr[n] = *(const bf16x8*)&Bs[cur][bro[n]];
#pragma unroll
        for (int m = 0; m < 4; ++m)
#pragma unroll
            for (int n = 0; n < 4; ++n)
                acc[m][n] = __builtin_amdgcn_mfma_f32_16x16x32_bf16(af[m], bfr[n], acc[m][n], 0, 0, 0);

        __builtin_amdgcn_s_barrier();
        asm volatile("" ::: "memory");
    }

    // epilogue: C/D layout col=lane&15, row=(lane>>4)*4+reg  [m89-verified]
#pragma unroll
    for (int m = 0; m < 4; ++m)
#pragma unroll
        for (int n = 0; n < 4; ++n) {
            const int col = j0 + wn * 64 + n * 16 + l15;
#pragma unroll
            for (int q = 0; q < 4; ++q) {
                const int row = i0 + wm * 64 + m * 16 + (lane >> 4) * 4 + q;
                C[(size_t)row * OUTF + col] = acc[m][n][q];
            }
        }
}

// ---------------- f32 GEMM fallback (known-good) ----------------
__global__ __launch_bounds__(256) void gemm_f32(const float* __restrict__ A,
                                                const float* __restrict__ B,
                                                float* __restrict__ C) {
    __shared__ float As[16][68];
    __shared__ float Bs[16][64];
    const int tid = threadIdx.x;
    const int tx = tid & 15, ty = tid >> 4;
    const int i0 = blockIdx.y * 64;
    const int j0 = blockIdx.x * 64;
    const int ar = tid >> 2;
    const int ac = (tid & 3) << 2;
    const int bk = tid >> 4;
    const int bc = (tid & 15) << 2;
    float acc[4][4] = {};
    for (int k0 = 0; k0 < IN_DIM; k0 += 16) {
        const float4 av = *(const float4*)(A + (size_t)(i0 + ar) * IN_DIM + k0 + ac);
        const float4 bv = *(const float4*)(B + (size_t)(k0 + bk) * OUTF + j0 + bc);
        __syncthreads();
        As[ac + 0][ar] = av.x; As[ac + 1][ar] = av.y;
        As[ac + 2][ar] = av.z; As[ac + 3][ar] = av.w;
        *(float4*)&Bs[bk][bc] = bv;
        __syncthreads();
#pragma unroll
        for (int k = 0; k < 16; ++k) {
            const float4 a4 = *(const float4*)&As[k][ty << 2];
            const float4 b4 = *(const float4*)&Bs[k][tx << 2];
            const float am[4] = {a4.x, a4.y, a4.z, a4.w};
            const float bn[4] = {b4.x, b4.y, b4.z, b4.w};
#pragma unroll
            for (int m = 0; m < 4; ++m)
#pragma unroll
                for (int n = 0; n < 4; ++n)
                    acc[m][n] = fmaf(am[m], bn[n], acc[m][n]);
        }
    }
#pragma unroll
    for (int m = 0; m < 4; ++m) {
        float4 v = {acc[m][0], acc[m][1], acc[m][2], acc[m][3]};
        *(float4*)(C + (size_t)(i0 + (ty << 2) + m) * OUTF + j0 + (tx << 2)) = v;
    }
}

// ---------------- el/er ----------------
__global__ __launch_bounds__(512) void el_er_kernel(const float* __restrict__ g,
                                                    const float* __restrict__ a,
                                                    float* __restrict__ el,
                                                    float* __restrict__ er) {
    const int i = blockIdx.x;
    const int wid = threadIdx.x >> 6;
    const int lane = threadIdx.x & 63;
    const float v = g[(size_t)i * OUTF + wid * HID + lane];
    float pl = v * a[lane];
    float pr = v * a[HID + lane];
#pragma unroll
    for (int off = 1; off < 64; off <<= 1) {
        pl += __shfl_xor(pl, off);
        pr += __shfl_xor(pr, off);
    }
    if (lane == 0) {
        el[(size_t)i * HEADS + wid] = pl;
        er[(size_t)i * HEADS + wid] = pr;
    }
}

// ---------------- sparse masked softmax + aggregation ----------------
// mode 0: bm = bitmask rows (512B/row). mode 1: adj int32 direct.
__global__ __launch_bounds__(512) void gat_attn(const unsigned long long* __restrict__ bm,
                                                const int* __restrict__ adj,
                                                const int mode,
                                                const float* __restrict__ g,
                                                const float* __restrict__ el,
                                                const float* __restrict__ er,
                                                float* __restrict__ out) {
    const int i = blockIdx.x;
    const int tid = threadIdx.x;
    const int lane = tid & 63;
    const int wid = tid >> 6;

    __shared__ int   nbr[MAXD];
    __shared__ float p[HEADS][MAXD];
    __shared__ int   wave_base[8];
    __shared__ int   s_deg;

    uint32_t msk;
    if (mode == 0) {
        msk = ((const unsigned char*)bm)[(size_t)i * 512 + tid];
    } else {
        const int4* row = (const int4*)(adj + (size_t)i * N_NODES);
        const int4 w0 = row[tid * 2 + 0];
        const int4 w1 = row[tid * 2 + 1];
        msk = 0;
        if (w0.x) msk |= 1u;   if (w0.y) msk |= 2u;
        if (w0.z) msk |= 4u;   if (w0.w) msk |= 8u;
        if (w1.x) msk |= 16u;  if (w1.y) msk |= 32u;
        if (w1.z) msk |= 64u;  if (w1.w) msk |= 128u;
    }

    const int c = __popc(msk);
    int inc = c;
#pragma unroll
    for (int off = 1; off < 64; off <<= 1) {
        const int t = __shfl_up(inc, off);
        if (lane >= off) inc += t;
    }
    if (lane == 63) wave_base[wid] = inc;
    __syncthreads();
    if (tid == 0) {
        int run = 0;
#pragma unroll
        for (int w = 0; w < 8; ++w) { const int t = wave_base[w]; wave_base[w] = run; run += t; }
        s_deg = run;
    }
    __syncthreads();
    int pos = wave_base[wid] + inc - c;
#pragma unroll
    for (int b = 0; b < 8; ++b) {
        if (msk & (1u << b)) {
            if (pos < MAXD) nbr[pos] = tid * 8 + b;
            ++pos;
        }
    }
    __syncthreads();
    const int deg = min(s_deg, MAXD);

    const float eli = el[(size_t)i * HEADS + wid];
    float m = -1e30f;
    for (int j = lane; j < deg; j += 64) {
        float e = eli + er[(size_t)nbr[j] * HEADS + wid];
        e = (e >= 0.f) ? e : SLOPE * e;
        m = fmaxf(m, e);
    }
#pragma unroll
    for (int off = 1; off < 64; off <<= 1) m = fmaxf(m, __shfl_xor(m, off));

    float s = 0.f;
    for (int j = lane; j < deg; j += 64) {
        float e = eli + er[(size_t)nbr[j] * HEADS + wid];
        e = (e >= 0.f) ? e : SLOPE * e;
        const float pe = __expf(e - m);
        p[wid][j] = pe;
        s += pe;
    }
#pragma unroll
    for (int off = 1; off < 64; off <<= 1) s += __shfl_xor(s, off);
    const float inv = 1.f / s;
    __syncthreads();

    float acc = 0.f;
    const float* gh = g + (size_t)wid * HID + lane;
#pragma unroll 8
    for (int j = 0; j < deg; ++j) {
        acc = fmaf(p[wid][j], gh[(size_t)nbr[j] * OUTF], acc);
    }
    out[(size_t)i * OUTF + wid * HID + lane] = acc * inv;
}

extern "C" void kernel_launch(void* const* d_in, const int* in_sizes, int n_in,
                              void* d_out, int out_size, void* d_ws, size_t ws_size,
                              hipStream_t stream) {
    const float* h   = (const float*)d_in[0];
    const int*   adj = (const int*)d_in[1];
    const float* W   = (const float*)d_in[2];
    const float* a   = (const float*)d_in[3];
    float* out = (float*)d_out;
    char* ws = (char*)d_ws;

    // workspace layout (bytes)
    const size_t G_OFF   = 0;         // 8 MB f32 g
    const size_t EL_OFF  = 8388608;   // 128 KB
    const size_t ER_OFF  = 8519680;   // 128 KB
    const size_t BM_OFF  = 8650752;   // 2 MB bitmask
    const size_t HHI_OFF = 10747904;  // 4 MB
    const size_t HLO_OFF = 14942208;  // 4 MB
    const size_t WHI_OFF = 19136512;  // 512 KB
    const size_t WLO_OFF = 19660800;  // 512 KB
    const size_t NEED_BM   = 10747904;
    const size_t NEED_FULL = 20185088;

    float* g  = (float*)(ws + G_OFF);
    float* el = (float*)(ws + EL_OFF);
    float* er = (float*)(ws + ER_OFF);
    unsigned long long* bm = (unsigned long long*)(ws + BM_OFF);

    const bool full = ws_size >= NEED_FULL;
    const bool bmok = ws_size >= NEED_BM;

    if (full) {
        unsigned short* hhi  = (unsigned short*)(ws + HHI_OFF);
        unsigned short* hlo  = (unsigned short*)(ws + HLO_OFF);
        unsigned short* whiT = (unsigned short*)(ws + WHI_OFF);
        unsigned short* wloT = (unsigned short*)(ws + WLO_OFF);
        conv_h<<<2048, 256, 0, stream>>>(h, hhi, hlo);
        conv_wT<<<dim3(8, 8), 256, 0, stream>>>(W, whiT, wloT);
        pack_adj<<<4096, 256, 0, stream>>>(adj, (unsigned short*)bm);
        gemm_mfma<<<dim3(4, 32), 256, 0, stream>>>((const bf16_t*)hhi, (const bf16_t*)hlo,
                                                   (const bf16_t*)whiT, (const bf16_t*)wloT, g);
        el_er_kernel<<<N_NODES, 512, 0, stream>>>(g, a, el, er);
        gat_attn<<<N_NODES, 512, 0, stream>>>(bm, adj, 0, g, el, er, out);
    } else {
        if (bmok) pack_adj<<<4096, 256, 0, stream>>>(adj, (unsigned short*)bm);
        gemm_f32<<<dim3(8, 64), 256, 0, stream>>>(h, W, g);
        el_er_kernel<<<N_NODES, 512, 0, stream>>>(g, a, el, er);
        gat_attn<<<N_NODES, 512, 0, stream>>>(bm, adj, bmok ? 0 : 1, g, el, er, out);
    }
}

// Round 4
// 72.366 us; speedup vs baseline: 1.4595x; 1.4595x over previous
//
#include <hip/hip_runtime.h>
#include <cstdint>
#include <cstddef>

#define N_NODES 4096
#define IN_DIM  512
#define HEADS   8
#define HID     64
#define OUTF    (HEADS * HID)   // 512
#define SLOPE   0.2f
#define MAXD    256             // degree ~ Binom(4096,0.01): mean 41, P(>255) ~ 0

typedef __bf16 bf16_t;
typedef __attribute__((ext_vector_type(8))) __bf16 bf16x8;
typedef __attribute__((ext_vector_type(4))) float    f32x4;

#define GLD16(gp, lp)                                                                  \
    __builtin_amdgcn_global_load_lds((const __attribute__((address_space(1))) void*)(gp), \
                                     (__attribute__((address_space(3))) void*)(lp), 16, 0, 0)

__device__ __forceinline__ unsigned short to_bf16_u(float x) {
    uint32_t u = __builtin_bit_cast(uint32_t, x);
    u += 0x7fffu + ((u >> 16) & 1u);
    return (unsigned short)(u >> 16);
}
__device__ __forceinline__ float bfbits_to_f(unsigned short b) {
    uint32_t u = ((uint32_t)b) << 16;
    return __builtin_bit_cast(float, u);
}

// ---------------- pack adj (int32) -> bitmask, 1 bit/col ----------------
__global__ __launch_bounds__(256) void pack_adj(const int* __restrict__ adj,
                                                unsigned short* __restrict__ bm16) {
    const int t = blockIdx.x * 256 + threadIdx.x;          // 0 .. 1048575
    const int4* src = (const int4*)adj + (size_t)t * 4;
    const int4 v0 = src[0], v1 = src[1], v2 = src[2], v3 = src[3];
    uint32_t b = 0;
    b |= (v0.x != 0) ? 1u << 0 : 0;  b |= (v0.y != 0) ? 1u << 1 : 0;
    b |= (v0.z != 0) ? 1u << 2 : 0;  b |= (v0.w != 0) ? 1u << 3 : 0;
    b |= (v1.x != 0) ? 1u << 4 : 0;  b |= (v1.y != 0) ? 1u << 5 : 0;
    b |= (v1.z != 0) ? 1u << 6 : 0;  b |= (v1.w != 0) ? 1u << 7 : 0;
    b |= (v2.x != 0) ? 1u << 8 : 0;  b |= (v2.y != 0) ? 1u << 9 : 0;
    b |= (v2.z != 0) ? 1u << 10 : 0; b |= (v2.w != 0) ? 1u << 11 : 0;
    b |= (v3.x != 0) ? 1u << 12 : 0; b |= (v3.y != 0) ? 1u << 13 : 0;
    b |= (v3.z != 0) ? 1u << 14 : 0; b |= (v3.w != 0) ? 1u << 15 : 0;
    bm16[t] = (unsigned short)b;
}

// ---------------- h (f32) -> h_hi (bf16) ----------------
__global__ __launch_bounds__(256) void conv_h(const float* __restrict__ h,
                                              unsigned short* __restrict__ hhi) {
    const int t = blockIdx.x * 256 + threadIdx.x;          // 0 .. 524287
    const float4 v = ((const float4*)h)[t];
    ushort4 hi;
    hi.x = to_bf16_u(v.x);
    hi.y = to_bf16_u(v.y);
    hi.z = to_bf16_u(v.z);
    hi.w = to_bf16_u(v.w);
    ((ushort4*)hhi)[t] = hi;
}

// ---------------- W (f32 [k][c]) -> W_hiT, W_loT (bf16 [c][k]) ----------------
__global__ __launch_bounds__(256) void conv_wT(const float* __restrict__ W,
                                               unsigned short* __restrict__ whiT,
                                               unsigned short* __restrict__ wloT) {
    __shared__ unsigned short shi[64][68];
    __shared__ unsigned short slo[64][68];
    const int tid = threadIdx.x;
    const int kt = blockIdx.y * 64;
    const int ct = blockIdx.x * 64;
#pragma unroll
    for (int rr = 0; rr < 4; ++rr) {
        const int lk = rr * 16 + (tid >> 4);
        const int lc = (tid & 15) * 4;
        const float4 v = *(const float4*)&W[(size_t)(kt + lk) * OUTF + ct + lc];
        shi[lk][lc + 0] = to_bf16_u(v.x); slo[lk][lc + 0] = to_bf16_u(v.x - bfbits_to_f(shi[lk][lc + 0]));
        shi[lk][lc + 1] = to_bf16_u(v.y); slo[lk][lc + 1] = to_bf16_u(v.y - bfbits_to_f(shi[lk][lc + 1]));
        shi[lk][lc + 2] = to_bf16_u(v.z); slo[lk][lc + 2] = to_bf16_u(v.z - bfbits_to_f(shi[lk][lc + 2]));
        shi[lk][lc + 3] = to_bf16_u(v.w); slo[lk][lc + 3] = to_bf16_u(v.w - bfbits_to_f(shi[lk][lc + 3]));
    }
    __syncthreads();
#pragma unroll
    for (int rr = 0; rr < 4; ++rr) {
        const int lc = rr * 16 + (tid >> 4);
        const int lk = (tid & 15) * 4;
        ushort4 hv, lv;
        hv.x = shi[lk + 0][lc]; hv.y = shi[lk + 1][lc]; hv.z = shi[lk + 2][lc]; hv.w = shi[lk + 3][lc];
        lv.x = slo[lk + 0][lc]; lv.y = slo[lk + 1][lc]; lv.z = slo[lk + 2][lc]; lv.w = slo[lk + 3][lc];
        *(ushort4*)&whiT[(size_t)(ct + lc) * IN_DIM + kt + lk] = hv;
        *(ushort4*)&wloT[(size_t)(ct + lc) * IN_DIM + kt + lk] = lv;
    }
}

// ---------------- MFMA GEMM: g = h_hi@(W_hi + W_lo), fused el/er ----------------
// Tile 128x64 (BN=64 == one head), BK=32, grid (8,32)=256 blocks (1/CU).
// 4 waves, wave tile 32x64 = 2x4 frags of 16x16x32. A staged ONCE per K-step,
// used against both Bhi and Blo. Chunk swizzle c^((row>>1)&3) on both sides.
__global__ __launch_bounds__(256) void gemm_mfma(const bf16_t* __restrict__ Ahi,
                                                 const bf16_t* __restrict__ BhiT,
                                                 const bf16_t* __restrict__ BloT,
                                                 const float* __restrict__ a,
                                                 float* __restrict__ C,
                                                 float* __restrict__ el,
                                                 float* __restrict__ er) {
    __shared__ bf16_t As[2][128 * 32];   // 8 KB each
    __shared__ bf16_t Bh[2][64 * 32];    // 4 KB each
    __shared__ bf16_t Bl[2][64 * 32];    // 4 KB each

    const int tid = threadIdx.x;
    const int wid = tid >> 6;
    const int lane = tid & 63;
    const int i0 = blockIdx.y * 128;
    const int j0 = blockIdx.x * 64;      // == head * 64
    const int l15 = lane & 15, kq = lane >> 4;

    // staging: wave w stages 16 rows per GLD16 call; lane -> (row, swz chunk)
    const int srow = wid * 16 + (lane >> 2);              // 0..63
    const int sc   = (lane & 3) ^ ((srow >> 1) & 3);      // swizzled chunk (row+64 same swz)
    const size_t aoff = (size_t)(i0 + srow) * IN_DIM + sc * 8;
    const size_t boff = (size_t)(j0 + srow) * IN_DIM + sc * 8;

    // fragment read offsets (elements)
    int aro[2], bro[4];
#pragma unroll
    for (int m = 0; m < 2; ++m) {
        const int row = wid * 32 + m * 16 + l15;
        aro[m] = row * 32 + (kq ^ ((row >> 1) & 3)) * 8;
    }
#pragma unroll
    for (int n = 0; n < 4; ++n) {
        const int col = n * 16 + l15;
        bro[n] = col * 32 + (kq ^ ((col >> 1) & 3)) * 8;
    }

    f32x4 acc[2][4] = {};

    auto stage = [&](int buf, int t) {
        const size_t k0 = (size_t)t * 32;
        GLD16(Ahi + aoff + k0,                        &As[buf][(wid * 16) * 32]);
        GLD16(Ahi + aoff + (size_t)64 * IN_DIM + k0,  &As[buf][(64 + wid * 16) * 32]);
        GLD16(BhiT + boff + k0,                       &Bh[buf][(wid * 16) * 32]);
        GLD16(BloT + boff + k0,                       &Bl[buf][(wid * 16) * 32]);
    };

    stage(0, 0);
    for (int t = 0; t < 16; ++t) {
        const int cur = t & 1;
        if (t < 15) {
            stage(cur ^ 1, t + 1);
            asm volatile("s_waitcnt vmcnt(4)" ::: "memory");
        } else {
            asm volatile("s_waitcnt vmcnt(0)" ::: "memory");
        }
        __builtin_amdgcn_s_barrier();
        asm volatile("" ::: "memory");

        bf16x8 af[2], bhf[4], blf[4];
#pragma unroll
        for (int m = 0; m < 2; ++m) af[m] = *(const bf16x8*)&As[cur][aro[m]];
#pragma unroll
        for (int n = 0; n < 4; ++n) bhf[n] = *(const bf16x8*)&Bh[cur][bro[n]];
#pragma unroll
        for (int n = 0; n < 4; ++n) blf[n] = *(const bf16x8*)&Bl[cur][bro[n]];
#pragma unroll
        for (int m = 0; m < 2; ++m)
#pragma unroll
            for (int n = 0; n < 4; ++n) {
                acc[m][n] = __builtin_amdgcn_mfma_f32_16x16x32_bf16(af[m], bhf[n], acc[m][n], 0, 0, 0);
                acc[m][n] = __builtin_amdgcn_mfma_f32_16x16x32_bf16(af[m], blf[n], acc[m][n], 0, 0, 0);
            }

        __builtin_amdgcn_s_barrier();
        asm volatile("" ::: "memory");
    }

    // ---- write g (C/D layout: col=lane&15, row=(lane>>4)*4+reg) ----
#pragma unroll
    for (int m = 0; m < 2; ++m)
#pragma unroll
        for (int n = 0; n < 4; ++n) {
            const int col = j0 + n * 16 + l15;
#pragma unroll
            for (int q = 0; q < 4; ++q) {
                const int row = i0 + wid * 32 + m * 16 + (lane >> 4) * 4 + q;
                C[(size_t)row * OUTF + col] = acc[m][n][q];
            }
        }

    // ---- fused el/er: block owns the whole head (64 cols) ----
    float al4[4], ar4[4];
#pragma unroll
    for (int n = 0; n < 4; ++n) {
        al4[n] = a[n * 16 + l15];
        ar4[n] = a[64 + n * 16 + l15];
    }
#pragma unroll
    for (int m = 0; m < 2; ++m)
#pragma unroll
        for (int q = 0; q < 4; ++q) {
            float pe = 0.f, pr = 0.f;
#pragma unroll
            for (int n = 0; n < 4; ++n) {
                const float v = acc[m][n][q];
                pe = fmaf(v, al4[n], pe);
                pr = fmaf(v, ar4[n], pr);
            }
#pragma unroll
            for (int off = 1; off < 16; off <<= 1) {
                pe += __shfl_xor(pe, off);
                pr += __shfl_xor(pr, off);
            }
            if (l15 == 0) {
                const int row = i0 + wid * 32 + m * 16 + (lane >> 4) * 4 + q;
                el[(size_t)row * HEADS + blockIdx.x] = pe;
                er[(size_t)row * HEADS + blockIdx.x] = pr;
            }
        }
}

// ---------------- f32 GEMM fallback ----------------
__global__ __launch_bounds__(256) void gemm_f32(const float* __restrict__ A,
                                                const float* __restrict__ B,
                                                float* __restrict__ C) {
    __shared__ float As[16][68];
    __shared__ float Bs[16][64];
    const int tid = threadIdx.x;
    const int tx = tid & 15, ty = tid >> 4;
    const int i0 = blockIdx.y * 64;
    const int j0 = blockIdx.x * 64;
    const int ar = tid >> 2;
    const int ac = (tid & 3) << 2;
    const int bk = tid >> 4;
    const int bc = (tid & 15) << 2;
    float acc[4][4] = {};
    for (int k0 = 0; k0 < IN_DIM; k0 += 16) {
        const float4 av = *(const float4*)(A + (size_t)(i0 + ar) * IN_DIM + k0 + ac);
        const float4 bv = *(const float4*)(B + (size_t)(k0 + bk) * OUTF + j0 + bc);
        __syncthreads();
        As[ac + 0][ar] = av.x; As[ac + 1][ar] = av.y;
        As[ac + 2][ar] = av.z; As[ac + 3][ar] = av.w;
        *(float4*)&Bs[bk][bc] = bv;
        __syncthreads();
#pragma unroll
        for (int k = 0; k < 16; ++k) {
            const float4 a4 = *(const float4*)&As[k][ty << 2];
            const float4 b4 = *(const float4*)&Bs[k][tx << 2];
            const float am[4] = {a4.x, a4.y, a4.z, a4.w};
            const float bn[4] = {b4.x, b4.y, b4.z, b4.w};
#pragma unroll
            for (int m = 0; m < 4; ++m)
#pragma unroll
                for (int n = 0; n < 4; ++n)
                    acc[m][n] = fmaf(am[m], bn[n], acc[m][n]);
        }
    }
#pragma unroll
    for (int m = 0; m < 4; ++m) {
        float4 v = {acc[m][0], acc[m][1], acc[m][2], acc[m][3]};
        *(float4*)(C + (size_t)(i0 + (ty << 2) + m) * OUTF + j0 + (tx << 2)) = v;
    }
}

// ---------------- el/er (fallback path only) ----------------
__global__ __launch_bounds__(512) void el_er_kernel(const float* __restrict__ g,
                                                    const float* __restrict__ a,
                                                    float* __restrict__ el,
                                                    float* __restrict__ er) {
    const int i = blockIdx.x;
    const int wid = threadIdx.x >> 6;
    const int lane = threadIdx.x & 63;
    const float v = g[(size_t)i * OUTF + wid * HID + lane];
    float pl = v * a[lane];
    float pr = v * a[HID + lane];
#pragma unroll
    for (int off = 1; off < 64; off <<= 1) {
        pl += __shfl_xor(pl, off);
        pr += __shfl_xor(pr, off);
    }
    if (lane == 0) {
        el[(size_t)i * HEADS + wid] = pl;
        er[(size_t)i * HEADS + wid] = pr;
    }
}

// ---------------- sparse masked softmax + aggregation ----------------
// Phase 3 layout: wave w -> half=w>>2 (heads half*4..+3), jslot=w&3 (j strided 4).
// Lane: head_local=lane>>4, feat4=(lane&15)*4 -> float4 gather per lane.
__global__ __launch_bounds__(512) void gat_attn(const unsigned long long* __restrict__ bm,
                                                const int* __restrict__ adj,
                                                const int mode,
                                                const float* __restrict__ g,
                                                const float* __restrict__ el,
                                                const float* __restrict__ er,
                                                float* __restrict__ out) {
    const int i = blockIdx.x;
    const int tid = threadIdx.x;
    const int lane = tid & 63;
    const int wid = tid >> 6;

    __shared__ int   nbr[MAXD];
    __shared__ float p[HEADS][MAXD];
    __shared__ float red[8][256];
    __shared__ float sinv[8];
    __shared__ int   wave_base[8];
    __shared__ int   s_deg;

    // ---- build 8-bit occupancy mask ----
    uint32_t msk;
    if (mode == 0) {
        msk = ((const unsigned char*)bm)[(size_t)i * 512 + tid];
    } else {
        const int4* row = (const int4*)(adj + (size_t)i * N_NODES);
        const int4 w0 = row[tid * 2 + 0];
        const int4 w1 = row[tid * 2 + 1];
        msk = 0;
        if (w0.x) msk |= 1u;   if (w0.y) msk |= 2u;
        if (w0.z) msk |= 4u;   if (w0.w) msk |= 8u;
        if (w1.x) msk |= 16u;  if (w1.y) msk |= 32u;
        if (w1.z) msk |= 64u;  if (w1.w) msk |= 128u;
    }

    // ---- deterministic compaction ----
    const int c = __popc(msk);
    int inc = c;
#pragma unroll
    for (int off = 1; off < 64; off <<= 1) {
        const int t = __shfl_up(inc, off);
        if (lane >= off) inc += t;
    }
    if (lane == 63) wave_base[wid] = inc;
    __syncthreads();
    if (tid == 0) {
        int run = 0;
#pragma unroll
        for (int w = 0; w < 8; ++w) { const int t = wave_base[w]; wave_base[w] = run; run += t; }
        s_deg = run;
    }
    __syncthreads();
    int pos = wave_base[wid] + inc - c;
#pragma unroll
    for (int b = 0; b < 8; ++b) {
        if (msk & (1u << b)) {
            if (pos < MAXD) nbr[pos] = tid * 8 + b;
            ++pos;
        }
    }
    __syncthreads();
    const int deg = min(s_deg, MAXD);

    // ---- per-head softmax (wave == head); cache raw e in p[] ----
    const float eli = el[(size_t)i * HEADS + wid];
    float m = -1e30f;
    for (int j = lane; j < deg; j += 64) {
        float e = eli + er[(size_t)nbr[j] * HEADS + wid];
        e = (e >= 0.f) ? e : SLOPE * e;
        p[wid][j] = e;
        m = fmaxf(m, e);
    }
#pragma unroll
    for (int off = 1; off < 64; off <<= 1) m = fmaxf(m, __shfl_xor(m, off));

    float s = 0.f;
    for (int j = lane; j < deg; j += 64) {
        const float pe = __expf(p[wid][j] - m);
        p[wid][j] = pe;
        s += pe;
    }
#pragma unroll
    for (int off = 1; off < 64; off <<= 1) s += __shfl_xor(s, off);
    if (lane == 0) sinv[wid] = 1.f / s;
    __syncthreads();   // p[], sinv visible to all waves

    // ---- gather: float4/lane, 4 j-slots in flight ----
    const int half = wid >> 2, jslot = wid & 3;
    const int head = half * 4 + (lane >> 4);
    const int f4 = (lane & 15) * 4;
    const float* gbase = g + (size_t)head * HID + f4;   // + node*OUTF per j
    float4 acc = {0.f, 0.f, 0.f, 0.f};
#pragma unroll 4
    for (int j = jslot; j < deg; j += 4) {
        const int nj = nbr[j];
        const float w = p[head][j];
        const float4 v = *(const float4*)(gbase + (size_t)nj * OUTF);
        acc.x = fmaf(w, v.x, acc.x);
        acc.y = fmaf(w, v.y, acc.y);
        acc.z = fmaf(w, v.z, acc.z);
        acc.w = fmaf(w, v.w, acc.w);
    }
    *(float4*)&red[wid][(lane >> 4) * 64 + f4] = acc;
    __syncthreads();

    // ---- cross-jslot reduce + scale + store ----
    const int hf = tid >> 8, loc = tid & 255;
    const float v = red[hf * 4 + 0][loc] + red[hf * 4 + 1][loc] +
                    red[hf * 4 + 2][loc] + red[hf * 4 + 3][loc];
    out[(size_t)i * OUTF + tid] = v * sinv[tid >> 6];
}

extern "C" void kernel_launch(void* const* d_in, const int* in_sizes, int n_in,
                              void* d_out, int out_size, void* d_ws, size_t ws_size,
                              hipStream_t stream) {
    const float* h   = (const float*)d_in[0];
    const int*   adj = (const int*)d_in[1];
    const float* W   = (const float*)d_in[2];
    const float* a   = (const float*)d_in[3];
    float* out = (float*)d_out;
    char* ws = (char*)d_ws;

    // workspace layout (bytes)
    const size_t G_OFF   = 0;         // 8 MB
    const size_t EL_OFF  = 8388608;   // 128 KB
    const size_t ER_OFF  = 8519680;   // 128 KB
    const size_t BM_OFF  = 8650752;   // 2 MB
    const size_t HHI_OFF = 10747904;  // 4 MB
    const size_t WHI_OFF = 14942208;  // 512 KB
    const size_t WLO_OFF = 15466496;  // 512 KB
    const size_t NEED_BM   = 10747904;
    const size_t NEED_FULL = 15990784;

    float* g  = (float*)(ws + G_OFF);
    float* el = (float*)(ws + EL_OFF);
    float* er = (float*)(ws + ER_OFF);
    unsigned long long* bm = (unsigned long long*)(ws + BM_OFF);

    const bool full = ws_size >= NEED_FULL;
    const bool bmok = ws_size >= NEED_BM;

    if (full) {
        unsigned short* hhi  = (unsigned short*)(ws + HHI_OFF);
        unsigned short* whiT = (unsigned short*)(ws + WHI_OFF);
        unsigned short* wloT = (unsigned short*)(ws + WLO_OFF);
        conv_h<<<2048, 256, 0, stream>>>(h, hhi);
        conv_wT<<<dim3(8, 8), 256, 0, stream>>>(W, whiT, wloT);
        pack_adj<<<4096, 256, 0, stream>>>(adj, (unsigned short*)bm);
        gemm_mfma<<<dim3(8, 32), 256, 0, stream>>>((const bf16_t*)hhi, (const bf16_t*)whiT,
                                                   (const bf16_t*)wloT, a, g, el, er);
        gat_attn<<<N_NODES, 512, 0, stream>>>(bm, adj, 0, g, el, er, out);
    } else {
        if (bmok) pack_adj<<<4096, 256, 0, stream>>>(adj, (unsigned short*)bm);
        gemm_f32<<<dim3(8, 64), 256, 0, stream>>>(h, W, g);
        el_er_kernel<<<N_NODES, 512, 0, stream>>>(g, a, el, er);
        gat_attn<<<N_NODES, 512, 0, stream>>>(bm, adj, bmok ? 0 : 1, g, el, er, out);
    }
}

// Round 5
// 55.904 us; speedup vs baseline: 1.8893x; 1.2945x over previous
//
#include <hip/hip_runtime.h>
#include <cstdint>
#include <cstddef>

#define N_NODES 4096
#define IN_DIM  512
#define HEADS   8
#define HID     64
#define OUTF    (HEADS * HID)   // 512
#define SLOPE   0.2f
#define MAXD    256             // degree ~ Binom(4096,0.01): mean 41, P(>255) ~ 0

typedef __bf16 bf16_t;
typedef __attribute__((ext_vector_type(8))) __bf16 bf16x8;
typedef __attribute__((ext_vector_type(4))) float    f32x4;

#define GLD16(gp, lp)                                                                  \
    __builtin_amdgcn_global_load_lds((const __attribute__((address_space(1))) void*)(gp), \
                                     (__attribute__((address_space(3))) void*)(lp), 16, 0, 0)

__device__ __forceinline__ unsigned short to_bf16_u(float x) {
    uint32_t u = __builtin_bit_cast(uint32_t, x);
    u += 0x7fffu + ((u >> 16) & 1u);
    return (unsigned short)(u >> 16);
}
__device__ __forceinline__ float bfbits_to_f(unsigned short b) {
    uint32_t u = ((uint32_t)b) << 16;
    return __builtin_bit_cast(float, u);
}

// ---------------- fused prep: conv_h | pack_adj | conv_wT ----------------
// blocks [0,2048): h f32 -> bf16 hi       (8 MB read, 4 MB write)
// blocks [2048,6144): adj int32 -> bitmask (64 MB read, 2 MB write)
// blocks [6144,6400): W -> W_hiT + W_loT   (1 MB read, 1 MB write, LDS-free)
__global__ __launch_bounds__(256) void prep(const float* __restrict__ h,
                                            unsigned short* __restrict__ hhi,
                                            const int* __restrict__ adj,
                                            unsigned short* __restrict__ bm16,
                                            const float* __restrict__ W,
                                            unsigned short* __restrict__ whiT,
                                            unsigned short* __restrict__ wloT) {
    const int b = blockIdx.x;
    const int tid = threadIdx.x;
    if (b < 2048) {
        const int t = b * 256 + tid;                       // 0 .. 524287
        const float4 v = ((const float4*)h)[t];
        ushort4 hi;
        hi.x = to_bf16_u(v.x); hi.y = to_bf16_u(v.y);
        hi.z = to_bf16_u(v.z); hi.w = to_bf16_u(v.w);
        ((ushort4*)hhi)[t] = hi;
    } else if (b < 6144) {
        const int t = (b - 2048) * 256 + tid;              // 0 .. 1048575
        const int4* src = (const int4*)adj + (size_t)t * 4;
        const int4 v0 = src[0], v1 = src[1], v2 = src[2], v3 = src[3];
        uint32_t m = 0;
        m |= (v0.x != 0) ? 1u << 0 : 0;  m |= (v0.y != 0) ? 1u << 1 : 0;
        m |= (v0.z != 0) ? 1u << 2 : 0;  m |= (v0.w != 0) ? 1u << 3 : 0;
        m |= (v1.x != 0) ? 1u << 4 : 0;  m |= (v1.y != 0) ? 1u << 5 : 0;
        m |= (v1.z != 0) ? 1u << 6 : 0;  m |= (v1.w != 0) ? 1u << 7 : 0;
        m |= (v2.x != 0) ? 1u << 8 : 0;  m |= (v2.y != 0) ? 1u << 9 : 0;
        m |= (v2.z != 0) ? 1u << 10 : 0; m |= (v2.w != 0) ? 1u << 11 : 0;
        m |= (v3.x != 0) ? 1u << 12 : 0; m |= (v3.y != 0) ? 1u << 13 : 0;
        m |= (v3.z != 0) ? 1u << 14 : 0; m |= (v3.w != 0) ? 1u << 15 : 0;
        bm16[t] = (unsigned short)m;
    } else {
        const int idx = (b - 6144) * 256 + tid;            // 0 .. 65535
        const int c   = idx & 511;
        const int kq  = (idx >> 9) * 4;                    // 0,4,..,508
        ushort4 hv, lv;
        float w0 = W[(size_t)(kq + 0) * OUTF + c];
        float w1 = W[(size_t)(kq + 1) * OUTF + c];
        float w2 = W[(size_t)(kq + 2) * OUTF + c];
        float w3 = W[(size_t)(kq + 3) * OUTF + c];
        hv.x = to_bf16_u(w0); lv.x = to_bf16_u(w0 - bfbits_to_f(hv.x));
        hv.y = to_bf16_u(w1); lv.y = to_bf16_u(w1 - bfbits_to_f(hv.y));
        hv.z = to_bf16_u(w2); lv.z = to_bf16_u(w2 - bfbits_to_f(hv.z));
        hv.w = to_bf16_u(w3); lv.w = to_bf16_u(w3 - bfbits_to_f(hv.w));
        *(ushort4*)&whiT[(size_t)c * IN_DIM + kq] = hv;
        *(ushort4*)&wloT[(size_t)c * IN_DIM + kq] = lv;
    }
}

// ---------------- MFMA GEMM: g(bf16) = h_hi@(W_hi + W_lo), fused el/er ----------------
// Tile 128x64 (BN=64 == one head), BK=32, grid (8,32)=256 blocks (1/CU).
// 4 waves, wave tile 32x64 = 2x4 frags of 16x16x32. Chunk swizzle both sides.
__global__ __launch_bounds__(256) void gemm_mfma(const bf16_t* __restrict__ Ahi,
                                                 const bf16_t* __restrict__ BhiT,
                                                 const bf16_t* __restrict__ BloT,
                                                 const float* __restrict__ a,
                                                 unsigned short* __restrict__ Gb,
                                                 float* __restrict__ el,
                                                 float* __restrict__ er) {
    __shared__ bf16_t As[2][128 * 32];
    __shared__ bf16_t Bh[2][64 * 32];
    __shared__ bf16_t Bl[2][64 * 32];

    const int tid = threadIdx.x;
    const int wid = tid >> 6;
    const int lane = tid & 63;
    const int i0 = blockIdx.y * 128;
    const int j0 = blockIdx.x * 64;      // == head * 64
    const int l15 = lane & 15, kq = lane >> 4;

    const int srow = wid * 16 + (lane >> 2);
    const int sc   = (lane & 3) ^ ((srow >> 1) & 3);
    const size_t aoff = (size_t)(i0 + srow) * IN_DIM + sc * 8;
    const size_t boff = (size_t)(j0 + srow) * IN_DIM + sc * 8;

    int aro[2], bro[4];
#pragma unroll
    for (int m = 0; m < 2; ++m) {
        const int row = wid * 32 + m * 16 + l15;
        aro[m] = row * 32 + (kq ^ ((row >> 1) & 3)) * 8;
    }
#pragma unroll
    for (int n = 0; n < 4; ++n) {
        const int col = n * 16 + l15;
        bro[n] = col * 32 + (kq ^ ((col >> 1) & 3)) * 8;
    }

    f32x4 acc[2][4] = {};

    auto stage = [&](int buf, int t) {
        const size_t k0 = (size_t)t * 32;
        GLD16(Ahi + aoff + k0,                        &As[buf][(wid * 16) * 32]);
        GLD16(Ahi + aoff + (size_t)64 * IN_DIM + k0,  &As[buf][(64 + wid * 16) * 32]);
        GLD16(BhiT + boff + k0,                       &Bh[buf][(wid * 16) * 32]);
        GLD16(BloT + boff + k0,                       &Bl[buf][(wid * 16) * 32]);
    };

    stage(0, 0);
    for (int t = 0; t < 16; ++t) {
        const int cur = t & 1;
        if (t < 15) {
            stage(cur ^ 1, t + 1);
            asm volatile("s_waitcnt vmcnt(4)" ::: "memory");
        } else {
            asm volatile("s_waitcnt vmcnt(0)" ::: "memory");
        }
        __builtin_amdgcn_s_barrier();
        asm volatile("" ::: "memory");

        bf16x8 af[2], bhf[4], blf[4];
#pragma unroll
        for (int m = 0; m < 2; ++m) af[m] = *(const bf16x8*)&As[cur][aro[m]];
#pragma unroll
        for (int n = 0; n < 4; ++n) bhf[n] = *(const bf16x8*)&Bh[cur][bro[n]];
#pragma unroll
        for (int n = 0; n < 4; ++n) blf[n] = *(const bf16x8*)&Bl[cur][bro[n]];
#pragma unroll
        for (int m = 0; m < 2; ++m)
#pragma unroll
            for (int n = 0; n < 4; ++n) {
                acc[m][n] = __builtin_amdgcn_mfma_f32_16x16x32_bf16(af[m], bhf[n], acc[m][n], 0, 0, 0);
                acc[m][n] = __builtin_amdgcn_mfma_f32_16x16x32_bf16(af[m], blf[n], acc[m][n], 0, 0, 0);
            }

        __builtin_amdgcn_s_barrier();
        asm volatile("" ::: "memory");
    }

    // ---- write g as bf16 (C/D layout: col=lane&15, row=(lane>>4)*4+reg) ----
#pragma unroll
    for (int m = 0; m < 2; ++m)
#pragma unroll
        for (int n = 0; n < 4; ++n) {
            const int col = j0 + n * 16 + l15;
#pragma unroll
            for (int q = 0; q < 4; ++q) {
                const int row = i0 + wid * 32 + m * 16 + (lane >> 4) * 4 + q;
                Gb[(size_t)row * OUTF + col] = to_bf16_u(acc[m][n][q]);
            }
        }

    // ---- fused el/er (f32 accuracy; block owns whole head) ----
    float al4[4], ar4[4];
#pragma unroll
    for (int n = 0; n < 4; ++n) {
        al4[n] = a[n * 16 + l15];
        ar4[n] = a[64 + n * 16 + l15];
    }
#pragma unroll
    for (int m = 0; m < 2; ++m)
#pragma unroll
        for (int q = 0; q < 4; ++q) {
            float pe = 0.f, pr = 0.f;
#pragma unroll
            for (int n = 0; n < 4; ++n) {
                const float v = acc[m][n][q];
                pe = fmaf(v, al4[n], pe);
                pr = fmaf(v, ar4[n], pr);
            }
#pragma unroll
            for (int off = 1; off < 16; off <<= 1) {
                pe += __shfl_xor(pe, off);
                pr += __shfl_xor(pr, off);
            }
            if (l15 == 0) {
                const int row = i0 + wid * 32 + m * 16 + (lane >> 4) * 4 + q;
                el[(size_t)row * HEADS + blockIdx.x] = pe;
                er[(size_t)row * HEADS + blockIdx.x] = pr;
            }
        }
}

// ---------------- attn: bitmask compaction + softmax + full-row bf16 gather ----------------
// 8 waves. Softmax: wave == head. Gather: wave w handles j = w (mod 8); its 64
// lanes x 16B = one full 1KB g row (all 8 heads), perfectly coalesced, L2-resident.
__global__ __launch_bounds__(512) void gat_attn_bf16(const unsigned char* __restrict__ bm,
                                                     const unsigned short* __restrict__ Gb,
                                                     const float* __restrict__ el,
                                                     const float* __restrict__ er,
                                                     float* __restrict__ out) {
    const int i = blockIdx.x;
    const int tid = threadIdx.x;
    const int lane = tid & 63;
    const int wid = tid >> 6;

    __shared__ int   nbr[MAXD];
    __shared__ float p[HEADS][MAXD + 2];
    __shared__ float red[8][OUTF];
    __shared__ float sinv[8];
    __shared__ int   wave_base[8];
    __shared__ int   s_deg;

    // ---- mask byte + deterministic compaction ----
    uint32_t msk = bm[(size_t)i * 512 + tid];
    const int c = __popc(msk);
    int inc = c;
#pragma unroll
    for (int off = 1; off < 64; off <<= 1) {
        const int t = __shfl_up(inc, off);
        if (lane >= off) inc += t;
    }
    if (lane == 63) wave_base[wid] = inc;
    __syncthreads();
    if (tid == 0) {
        int run = 0;
#pragma unroll
        for (int w = 0; w < 8; ++w) { const int t = wave_base[w]; wave_base[w] = run; run += t; }
        s_deg = run;
    }
    __syncthreads();
    int pos = wave_base[wid] + inc - c;
#pragma unroll
    for (int b = 0; b < 8; ++b) {
        if (msk & (1u << b)) {
            if (pos < MAXD) nbr[pos] = tid * 8 + b;
            ++pos;
        }
    }
    __syncthreads();
    const int deg = min(s_deg, MAXD);

    // ---- per-head softmax (wave == head) ----
    const float eli = el[(size_t)i * HEADS + wid];
    float m = -1e30f;
    for (int j = lane; j < deg; j += 64) {
        float e = eli + er[(size_t)nbr[j] * HEADS + wid];
        e = (e >= 0.f) ? e : SLOPE * e;
        p[wid][j] = e;
        m = fmaxf(m, e);
    }
#pragma unroll
    for (int off = 1; off < 64; off <<= 1) m = fmaxf(m, __shfl_xor(m, off));

    float s = 0.f;
    for (int j = lane; j < deg; j += 64) {
        const float pe = __expf(p[wid][j] - m);
        p[wid][j] = pe;
        s += pe;
    }
#pragma unroll
    for (int off = 1; off < 64; off <<= 1) s += __shfl_xor(s, off);
    if (lane == 0) sinv[wid] = 1.f / s;
    __syncthreads();

    // ---- gather: wave w takes edges j = w, w+8, ...; lane covers 8 bf16 feats ----
    const int myhead = lane >> 3;           // p row for this lane's features
    float a8[8] = {};
    for (int j = wid; j < deg; j += 8) {
        const int nj = nbr[j];
        const float w = p[myhead][j];
        const uint4 v = *(const uint4*)(Gb + (size_t)nj * OUTF + lane * 8);
        a8[0] = fmaf(w, bfbits_to_f((unsigned short)(v.x & 0xffffu)), a8[0]);
        a8[1] = fmaf(w, bfbits_to_f((unsigned short)(v.x >> 16)),     a8[1]);
        a8[2] = fmaf(w, bfbits_to_f((unsigned short)(v.y & 0xffffu)), a8[2]);
        a8[3] = fmaf(w, bfbits_to_f((unsigned short)(v.y >> 16)),     a8[3]);
        a8[4] = fmaf(w, bfbits_to_f((unsigned short)(v.z & 0xffffu)), a8[4]);
        a8[5] = fmaf(w, bfbits_to_f((unsigned short)(v.z >> 16)),     a8[5]);
        a8[6] = fmaf(w, bfbits_to_f((unsigned short)(v.w & 0xffffu)), a8[6]);
        a8[7] = fmaf(w, bfbits_to_f((unsigned short)(v.w >> 16)),     a8[7]);
    }
    float4 lo = {a8[0], a8[1], a8[2], a8[3]};
    float4 hi = {a8[4], a8[5], a8[6], a8[7]};
    *(float4*)&red[wid][lane * 8 + 0] = lo;
    *(float4*)&red[wid][lane * 8 + 4] = hi;
    __syncthreads();

    // ---- cross-wave reduce + scale + store ----
    float v = 0.f;
#pragma unroll
    for (int w = 0; w < 8; ++w) v += red[w][tid];
    out[(size_t)i * OUTF + tid] = v * sinv[tid >> 6];
}

// ================= fallback path (f32, known-good) =================
__global__ __launch_bounds__(256) void gemm_f32(const float* __restrict__ A,
                                                const float* __restrict__ B,
                                                float* __restrict__ C) {
    __shared__ float As[16][68];
    __shared__ float Bs[16][64];
    const int tid = threadIdx.x;
    const int tx = tid & 15, ty = tid >> 4;
    const int i0 = blockIdx.y * 64;
    const int j0 = blockIdx.x * 64;
    const int ar = tid >> 2;
    const int ac = (tid & 3) << 2;
    const int bk = tid >> 4;
    const int bc = (tid & 15) << 2;
    float acc[4][4] = {};
    for (int k0 = 0; k0 < IN_DIM; k0 += 16) {
        const float4 av = *(const float4*)(A + (size_t)(i0 + ar) * IN_DIM + k0 + ac);
        const float4 bv = *(const float4*)(B + (size_t)(k0 + bk) * OUTF + j0 + bc);
        __syncthreads();
        As[ac + 0][ar] = av.x; As[ac + 1][ar] = av.y;
        As[ac + 2][ar] = av.z; As[ac + 3][ar] = av.w;
        *(float4*)&Bs[bk][bc] = bv;
        __syncthreads();
#pragma unroll
        for (int k = 0; k < 16; ++k) {
            const float4 a4 = *(const float4*)&As[k][ty << 2];
            const float4 b4 = *(const float4*)&Bs[k][tx << 2];
            const float am[4] = {a4.x, a4.y, a4.z, a4.w};
            const float bn[4] = {b4.x, b4.y, b4.z, b4.w};
#pragma unroll
            for (int m = 0; m < 4; ++m)
#pragma unroll
                for (int n = 0; n < 4; ++n)
                    acc[m][n] = fmaf(am[m], bn[n], acc[m][n]);
        }
    }
#pragma unroll
    for (int m = 0; m < 4; ++m) {
        float4 v = {acc[m][0], acc[m][1], acc[m][2], acc[m][3]};
        *(float4*)(C + (size_t)(i0 + (ty << 2) + m) * OUTF + j0 + (tx << 2)) = v;
    }
}

__global__ __launch_bounds__(512) void el_er_kernel(const float* __restrict__ g,
                                                    const float* __restrict__ a,
                                                    float* __restrict__ el,
                                                    float* __restrict__ er) {
    const int i = blockIdx.x;
    const int wid = threadIdx.x >> 6;
    const int lane = threadIdx.x & 63;
    const float v = g[(size_t)i * OUTF + wid * HID + lane];
    float pl = v * a[lane];
    float pr = v * a[HID + lane];
#pragma unroll
    for (int off = 1; off < 64; off <<= 1) {
        pl += __shfl_xor(pl, off);
        pr += __shfl_xor(pr, off);
    }
    if (lane == 0) {
        el[(size_t)i * HEADS + wid] = pl;
        er[(size_t)i * HEADS + wid] = pr;
    }
}

__global__ __launch_bounds__(512) void gat_attn_f32(const int* __restrict__ adj,
                                                    const float* __restrict__ g,
                                                    const float* __restrict__ el,
                                                    const float* __restrict__ er,
                                                    float* __restrict__ out) {
    const int i = blockIdx.x;
    const int tid = threadIdx.x;
    const int lane = tid & 63;
    const int wid = tid >> 6;

    __shared__ int   nbr[MAXD];
    __shared__ float p[HEADS][MAXD + 2];
    __shared__ float red[8][256];
    __shared__ float sinv[8];
    __shared__ int   wave_base[8];
    __shared__ int   s_deg;

    const int4* row = (const int4*)(adj + (size_t)i * N_NODES);
    const int4 w0 = row[tid * 2 + 0];
    const int4 w1 = row[tid * 2 + 1];
    uint32_t msk = 0;
    if (w0.x) msk |= 1u;   if (w0.y) msk |= 2u;
    if (w0.z) msk |= 4u;   if (w0.w) msk |= 8u;
    if (w1.x) msk |= 16u;  if (w1.y) msk |= 32u;
    if (w1.z) msk |= 64u;  if (w1.w) msk |= 128u;

    const int c = __popc(msk);
    int inc = c;
#pragma unroll
    for (int off = 1; off < 64; off <<= 1) {
        const int t = __shfl_up(inc, off);
        if (lane >= off) inc += t;
    }
    if (lane == 63) wave_base[wid] = inc;
    __syncthreads();
    if (tid == 0) {
        int run = 0;
#pragma unroll
        for (int w = 0; w < 8; ++w) { const int t = wave_base[w]; wave_base[w] = run; run += t; }
        s_deg = run;
    }
    __syncthreads();
    int pos = wave_base[wid] + inc - c;
#pragma unroll
    for (int b = 0; b < 8; ++b) {
        if (msk & (1u << b)) {
            if (pos < MAXD) nbr[pos] = tid * 8 + b;
            ++pos;
        }
    }
    __syncthreads();
    const int deg = min(s_deg, MAXD);

    const float eli = el[(size_t)i * HEADS + wid];
    float m = -1e30f;
    for (int j = lane; j < deg; j += 64) {
        float e = eli + er[(size_t)nbr[j] * HEADS + wid];
        e = (e >= 0.f) ? e : SLOPE * e;
        p[wid][j] = e;
        m = fmaxf(m, e);
    }
#pragma unroll
    for (int off = 1; off < 64; off <<= 1) m = fmaxf(m, __shfl_xor(m, off));
    float s = 0.f;
    for (int j = lane; j < deg; j += 64) {
        const float pe = __expf(p[wid][j] - m);
        p[wid][j] = pe;
        s += pe;
    }
#pragma unroll
    for (int off = 1; off < 64; off <<= 1) s += __shfl_xor(s, off);
    if (lane == 0) sinv[wid] = 1.f / s;
    __syncthreads();

    const int half = wid >> 2, jslot = wid & 3;
    const int head = half * 4 + (lane >> 4);
    const int f4 = (lane & 15) * 4;
    const float* gbase = g + (size_t)head * HID + f4;
    float4 acc = {0.f, 0.f, 0.f, 0.f};
#pragma unroll 4
    for (int j = jslot; j < deg; j += 4) {
        const int nj = nbr[j];
        const float w = p[head][j];
        const float4 v = *(const float4*)(gbase + (size_t)nj * OUTF);
        acc.x = fmaf(w, v.x, acc.x);
        acc.y = fmaf(w, v.y, acc.y);
        acc.z = fmaf(w, v.z, acc.z);
        acc.w = fmaf(w, v.w, acc.w);
    }
    *(float4*)&red[wid][(lane >> 4) * 64 + f4] = acc;
    __syncthreads();

    const int hf = tid >> 8, loc = tid & 255;
    const float v = red[hf * 4 + 0][loc] + red[hf * 4 + 1][loc] +
                    red[hf * 4 + 2][loc] + red[hf * 4 + 3][loc];
    out[(size_t)i * OUTF + tid] = v * sinv[tid >> 6];
}

extern "C" void kernel_launch(void* const* d_in, const int* in_sizes, int n_in,
                              void* d_out, int out_size, void* d_ws, size_t ws_size,
                              hipStream_t stream) {
    const float* h   = (const float*)d_in[0];
    const int*   adj = (const int*)d_in[1];
    const float* W   = (const float*)d_in[2];
    const float* a   = (const float*)d_in[3];
    float* out = (float*)d_out;
    char* ws = (char*)d_ws;

    // workspace layout (bytes)
    const size_t G_OFF   = 0;         // 8 MB region (bf16 path uses first 4 MB)
    const size_t EL_OFF  = 8388608;   // 128 KB
    const size_t ER_OFF  = 8519680;   // 128 KB
    const size_t BM_OFF  = 8650752;   // 2 MB
    const size_t HHI_OFF = 10747904;  // 4 MB
    const size_t WHI_OFF = 14942208;  // 512 KB
    const size_t WLO_OFF = 15466496;  // 512 KB
    const size_t NEED_FULL = 15990784;

    float* el = (float*)(ws + EL_OFF);
    float* er = (float*)(ws + ER_OFF);

    if (ws_size >= NEED_FULL) {
        unsigned short* gbf  = (unsigned short*)(ws + G_OFF);
        unsigned short* bm   = (unsigned short*)(ws + BM_OFF);
        unsigned short* hhi  = (unsigned short*)(ws + HHI_OFF);
        unsigned short* whiT = (unsigned short*)(ws + WHI_OFF);
        unsigned short* wloT = (unsigned short*)(ws + WLO_OFF);
        prep<<<6400, 256, 0, stream>>>(h, hhi, adj, bm, W, whiT, wloT);
        gemm_mfma<<<dim3(8, 32), 256, 0, stream>>>((const bf16_t*)hhi, (const bf16_t*)whiT,
                                                   (const bf16_t*)wloT, a, gbf, el, er);
        gat_attn_bf16<<<N_NODES, 512, 0, stream>>>((const unsigned char*)bm, gbf, el, er, out);
    } else {
        float* g = (float*)(ws + G_OFF);
        gemm_f32<<<dim3(8, 64), 256, 0, stream>>>(h, W, g);
        el_er_kernel<<<N_NODES, 512, 0, stream>>>(g, a, el, er);
        gat_attn_f32<<<N_NODES, 512, 0, stream>>>(adj, g, el, er, out);
    }
}

// Round 6
// 49.083 us; speedup vs baseline: 2.1518x; 1.1390x over previous
//
#include <hip/hip_runtime.h>
#include <cstdint>
#include <cstddef>

#define N_NODES 4096
#define IN_DIM  512
#define HEADS   8
#define HID     64
#define OUTF    (HEADS * HID)   // 512
#define SLOPE   0.2f
#define MAXD    256             // fallback path cap
#define MAXD2   128             // wave-attn cap: deg ~ Binom(4096,0.01) mean 41, 128 = 13.6 sigma

typedef __bf16 bf16_t;
typedef __attribute__((ext_vector_type(8))) __bf16 bf16x8;
typedef __attribute__((ext_vector_type(4))) float    f32x4;

#define GLD16(gp, lp)                                                                  \
    __builtin_amdgcn_global_load_lds((const __attribute__((address_space(1))) void*)(gp), \
                                     (__attribute__((address_space(3))) void*)(lp), 16, 0, 0)

__device__ __forceinline__ unsigned short to_bf16_u(float x) {
    uint32_t u = __builtin_bit_cast(uint32_t, x);
    u += 0x7fffu + ((u >> 16) & 1u);
    return (unsigned short)(u >> 16);
}
__device__ __forceinline__ float bfbits_to_f(unsigned short b) {
    uint32_t u = ((uint32_t)b) << 16;
    return __builtin_bit_cast(float, u);
}

// ---------------- prep_conv: h -> bf16 | W -> W_hiT/W_loT ----------------
// blocks [0,2048): h (8 MB read); blocks [2048,2304): W split-transpose (1 MB read)
__global__ __launch_bounds__(256) void prep_conv(const float* __restrict__ h,
                                                 unsigned short* __restrict__ hhi,
                                                 const float* __restrict__ W,
                                                 unsigned short* __restrict__ whiT,
                                                 unsigned short* __restrict__ wloT) {
    const int b = blockIdx.x;
    const int tid = threadIdx.x;
    if (b < 2048) {
        const int t = b * 256 + tid;                       // 0 .. 524287
        const float4 v = ((const float4*)h)[t];
        ushort4 hi;
        hi.x = to_bf16_u(v.x); hi.y = to_bf16_u(v.y);
        hi.z = to_bf16_u(v.z); hi.w = to_bf16_u(v.w);
        ((ushort4*)hhi)[t] = hi;
    } else {
        const int idx = (b - 2048) * 256 + tid;            // 0 .. 65535
        const int c   = idx & 511;
        const int kq  = (idx >> 9) * 4;                    // 0,4,..,508
        ushort4 hv, lv;
        float w0 = W[(size_t)(kq + 0) * OUTF + c];
        float w1 = W[(size_t)(kq + 1) * OUTF + c];
        float w2 = W[(size_t)(kq + 2) * OUTF + c];
        float w3 = W[(size_t)(kq + 3) * OUTF + c];
        hv.x = to_bf16_u(w0); lv.x = to_bf16_u(w0 - bfbits_to_f(hv.x));
        hv.y = to_bf16_u(w1); lv.y = to_bf16_u(w1 - bfbits_to_f(hv.y));
        hv.z = to_bf16_u(w2); lv.z = to_bf16_u(w2 - bfbits_to_f(hv.z));
        hv.w = to_bf16_u(w3); lv.w = to_bf16_u(w3 - bfbits_to_f(hv.w));
        *(ushort4*)&whiT[(size_t)c * IN_DIM + kq] = hv;
        *(ushort4*)&wloT[(size_t)c * IN_DIM + kq] = lv;
    }
}

// ---------------- fused gemm + pack_adj ----------------
// blocks [0,512): MFMA GEMM g(bf16) = h_hi @ (W_hi + W_lo), fused el/er.
//   64x64 tile, BK=32, 4 waves (2x2), wave tile 32x32 (2x2 frags of 16x16x32).
//   grid.x<512: bid -> (head = bid&7, row-tile = bid>>3). 2 blocks/CU resident.
// blocks [512,4608): adj int32 -> bitmask (64 MB stream overlapped with GEMM).
__global__ __launch_bounds__(256) void gemm_pack(const bf16_t* __restrict__ Ahi,
                                                 const bf16_t* __restrict__ BhiT,
                                                 const bf16_t* __restrict__ BloT,
                                                 const float* __restrict__ a,
                                                 unsigned short* __restrict__ Gb,
                                                 float* __restrict__ el,
                                                 float* __restrict__ er,
                                                 const int* __restrict__ adj,
                                                 unsigned short* __restrict__ bm16) {
    __shared__ bf16_t As[2][64 * 32];   // 4 KB each
    __shared__ bf16_t Bh[2][64 * 32];
    __shared__ bf16_t Bl[2][64 * 32];
    __shared__ float  elp[2][64], erp[2][64];

    const int tid = threadIdx.x;

    if (blockIdx.x >= 512) {            // ---- pack_adj part ----
        const int t = (blockIdx.x - 512) * 256 + tid;      // 0 .. 1048575
        const int4* src = (const int4*)adj + (size_t)t * 4;
        const int4 v0 = src[0], v1 = src[1], v2 = src[2], v3 = src[3];
        uint32_t m = 0;
        m |= (v0.x != 0) ? 1u << 0 : 0;  m |= (v0.y != 0) ? 1u << 1 : 0;
        m |= (v0.z != 0) ? 1u << 2 : 0;  m |= (v0.w != 0) ? 1u << 3 : 0;
        m |= (v1.x != 0) ? 1u << 4 : 0;  m |= (v1.y != 0) ? 1u << 5 : 0;
        m |= (v1.z != 0) ? 1u << 6 : 0;  m |= (v1.w != 0) ? 1u << 7 : 0;
        m |= (v2.x != 0) ? 1u << 8 : 0;  m |= (v2.y != 0) ? 1u << 9 : 0;
        m |= (v2.z != 0) ? 1u << 10 : 0; m |= (v2.w != 0) ? 1u << 11 : 0;
        m |= (v3.x != 0) ? 1u << 12 : 0; m |= (v3.y != 0) ? 1u << 13 : 0;
        m |= (v3.z != 0) ? 1u << 14 : 0; m |= (v3.w != 0) ? 1u << 15 : 0;
        bm16[t] = (unsigned short)m;
        return;
    }

    // ---- GEMM part ----
    const int wid = tid >> 6;
    const int lane = tid & 63;
    const int head = blockIdx.x & 7;
    const int i0 = (blockIdx.x >> 3) * 64;
    const int j0 = head * 64;
    const int l15 = lane & 15, kq = lane >> 4;

    // staging: thread t -> row t>>2, chunk t&3; fetch global chunk swizzled
    const int srow = tid >> 2;
    const int sc   = (tid & 3) ^ ((srow >> 1) & 3);
    const size_t aoff = (size_t)(i0 + srow) * IN_DIM + sc * 8;
    const size_t boff = (size_t)(j0 + srow) * IN_DIM + sc * 8;

    // fragment read offsets
    const int wm = wid >> 1, wn = wid & 1;
    int aro[2], bro[2];
#pragma unroll
    for (int m = 0; m < 2; ++m) {
        const int row = wm * 32 + m * 16 + l15;
        aro[m] = row * 32 + (kq ^ ((row >> 1) & 3)) * 8;
    }
#pragma unroll
    for (int n = 0; n < 2; ++n) {
        const int col = wn * 32 + n * 16 + l15;
        bro[n] = col * 32 + (kq ^ ((col >> 1) & 3)) * 8;
    }

    f32x4 acc[2][2] = {};

    auto stage = [&](int buf, int t) {
        const size_t k0 = (size_t)t * 32;
        GLD16(Ahi  + aoff + k0, &As[buf][tid * 8]);
        GLD16(BhiT + boff + k0, &Bh[buf][tid * 8]);
        GLD16(BloT + boff + k0, &Bl[buf][tid * 8]);
    };

    stage(0, 0);
    for (int t = 0; t < 16; ++t) {
        const int cur = t & 1;
        if (t < 15) {
            stage(cur ^ 1, t + 1);
            asm volatile("s_waitcnt vmcnt(3)" ::: "memory");
        } else {
            asm volatile("s_waitcnt vmcnt(0)" ::: "memory");
        }
        __builtin_amdgcn_s_barrier();
        asm volatile("" ::: "memory");

        bf16x8 af[2], bhf[2], blf[2];
#pragma unroll
        for (int m = 0; m < 2; ++m) af[m] = *(const bf16x8*)&As[cur][aro[m]];
#pragma unroll
        for (int n = 0; n < 2; ++n) bhf[n] = *(const bf16x8*)&Bh[cur][bro[n]];
#pragma unroll
        for (int n = 0; n < 2; ++n) blf[n] = *(const bf16x8*)&Bl[cur][bro[n]];
#pragma unroll
        for (int m = 0; m < 2; ++m)
#pragma unroll
            for (int n = 0; n < 2; ++n) {
                acc[m][n] = __builtin_amdgcn_mfma_f32_16x16x32_bf16(af[m], bhf[n], acc[m][n], 0, 0, 0);
                acc[m][n] = __builtin_amdgcn_mfma_f32_16x16x32_bf16(af[m], blf[n], acc[m][n], 0, 0, 0);
            }

        __builtin_amdgcn_s_barrier();
        asm volatile("" ::: "memory");
    }

    // ---- write g bf16 (C/D layout: col=lane&15, row=(lane>>4)*4+reg) ----
#pragma unroll
    for (int m = 0; m < 2; ++m)
#pragma unroll
        for (int n = 0; n < 2; ++n) {
            const int col = j0 + wn * 32 + n * 16 + l15;
#pragma unroll
            for (int q = 0; q < 4; ++q) {
                const int row = i0 + wm * 32 + m * 16 + kq * 4 + q;
                Gb[(size_t)row * OUTF + col] = to_bf16_u(acc[m][n][q]);
            }
        }

    // ---- fused el/er: wave covers 32 cols; cross-wave-pair reduce via LDS ----
    float al[2], arr[2];
#pragma unroll
    for (int n = 0; n < 2; ++n) {
        al[n]  = a[wn * 32 + n * 16 + l15];
        arr[n] = a[64 + wn * 32 + n * 16 + l15];
    }
#pragma unroll
    for (int m = 0; m < 2; ++m)
#pragma unroll
        for (int q = 0; q < 4; ++q) {
            float pe = 0.f, pr = 0.f;
#pragma unroll
            for (int n = 0; n < 2; ++n) {
                const float v = acc[m][n][q];
                pe = fmaf(v, al[n], pe);
                pr = fmaf(v, arr[n], pr);
            }
#pragma unroll
            for (int off = 1; off < 16; off <<= 1) {
                pe += __shfl_xor(pe, off);
                pr += __shfl_xor(pr, off);
            }
            if (l15 == 0) {
                const int lrow = wm * 32 + m * 16 + kq * 4 + q;
                elp[wn][lrow] = pe;
                erp[wn][lrow] = pr;
            }
        }
    __syncthreads();
    if (tid < 64) {
        el[(size_t)(i0 + tid) * HEADS + head] = elp[0][tid] + elp[1][tid];
        er[(size_t)(i0 + tid) * HEADS + head] = erp[0][tid] + erp[1][tid];
    }
}

// ---------------- wave-per-row attn: barrier-free ----------------
// 512 blocks x 8 waves; wave w of block b owns row i = b*8+w for ALL 8 heads.
// Compaction from u64 bitmask; softmax 8-heads-wide in registers; gather:
// 64 lanes x 16B = one full 1KB bf16 g row per load instruction.
__global__ __launch_bounds__(512) void gat_attn_wave(const unsigned long long* __restrict__ bm64,
                                                     const unsigned short* __restrict__ Gb,
                                                     const float* __restrict__ el,
                                                     const float* __restrict__ er,
                                                     float* __restrict__ out) {
    __shared__ float pw[8][8][MAXD2 + 8];   // [wave][head][j], +8 pad de-banks gather read
    __shared__ int   nbr[8][MAXD2];
    const int tid = threadIdx.x;
    const int lane = tid & 63;
    const int wid = tid >> 6;
    const int i = blockIdx.x * 8 + wid;

    // ---- compaction: lane l owns cols 64l..64l+63 ----
    unsigned long long q = bm64[(size_t)i * 64 + lane];
    const int c = __popcll(q);
    int inc = c;
#pragma unroll
    for (int off = 1; off < 64; off <<= 1) {
        const int t = __shfl_up(inc, off);
        if (lane >= off) inc += t;
    }
    const int deg = min(__shfl(inc, 63), MAXD2);
    int pos = inc - c;
    while (q) {
        const int b = __builtin_ctzll(q);
        q &= q - 1;
        if (pos < MAXD2) nbr[wid][pos] = lane * 64 + b;
        ++pos;
    }
    asm volatile("s_waitcnt lgkmcnt(0)" ::: "memory");
    __builtin_amdgcn_wave_barrier();

    // ---- softmax pass 1: raw scores + running max (8 heads wide) ----
    const float4 el_lo = *(const float4*)(el + (size_t)i * 8);
    const float4 el_hi = *(const float4*)(el + (size_t)i * 8 + 4);
    float mx[8];
#pragma unroll
    for (int h = 0; h < 8; ++h) mx[h] = -1e30f;
    for (int j = lane; j < deg; j += 64) {
        const int nj = nbr[wid][j];
        const float4 er_lo = *(const float4*)(er + (size_t)nj * 8);
        const float4 er_hi = *(const float4*)(er + (size_t)nj * 8 + 4);
        float e[8] = {el_lo.x + er_lo.x, el_lo.y + er_lo.y, el_lo.z + er_lo.z, el_lo.w + er_lo.w,
                      el_hi.x + er_hi.x, el_hi.y + er_hi.y, el_hi.z + er_hi.z, el_hi.w + er_hi.w};
#pragma unroll
        for (int h = 0; h < 8; ++h) {
            e[h] = (e[h] >= 0.f) ? e[h] : SLOPE * e[h];
            pw[wid][h][j] = e[h];
            mx[h] = fmaxf(mx[h], e[h]);
        }
    }
#pragma unroll
    for (int off = 1; off < 64; off <<= 1)
#pragma unroll
        for (int h = 0; h < 8; ++h) mx[h] = fmaxf(mx[h], __shfl_xor(mx[h], off));

    // ---- pass 2: exp + sums ----
    float s8[8] = {};
    for (int j = lane; j < deg; j += 64) {
#pragma unroll
        for (int h = 0; h < 8; ++h) {
            const float pe = __expf(pw[wid][h][j] - mx[h]);
            pw[wid][h][j] = pe;
            s8[h] += pe;
        }
    }
#pragma unroll
    for (int off = 1; off < 64; off <<= 1)
#pragma unroll
        for (int h = 0; h < 8; ++h) s8[h] += __shfl_xor(s8[h], off);
    asm volatile("s_waitcnt lgkmcnt(0)" ::: "memory");
    __builtin_amdgcn_wave_barrier();

    // ---- gather: lane covers feats lane*8..+7 (head = lane>>3) ----
    const int myhead = lane >> 3;
    float sv = s8[0];                       // static-index select chain (rule #20)
    sv = (myhead == 1) ? s8[1] : sv;
    sv = (myhead == 2) ? s8[2] : sv;
    sv = (myhead == 3) ? s8[3] : sv;
    sv = (myhead == 4) ? s8[4] : sv;
    sv = (myhead == 5) ? s8[5] : sv;
    sv = (myhead == 6) ? s8[6] : sv;
    sv = (myhead == 7) ? s8[7] : sv;
    const float inv = 1.f / sv;

    float a8[8] = {};
    const unsigned short* gl = Gb + lane * 8;
#pragma unroll 2
    for (int j = 0; j < deg; ++j) {
        const int nj = nbr[wid][j];
        const float w = pw[wid][myhead][j];
        const uint4 v = *(const uint4*)(gl + (size_t)nj * OUTF);
        a8[0] = fmaf(w, bfbits_to_f((unsigned short)(v.x & 0xffffu)), a8[0]);
        a8[1] = fmaf(w, bfbits_to_f((unsigned short)(v.x >> 16)),     a8[1]);
        a8[2] = fmaf(w, bfbits_to_f((unsigned short)(v.y & 0xffffu)), a8[2]);
        a8[3] = fmaf(w, bfbits_to_f((unsigned short)(v.y >> 16)),     a8[3]);
        a8[4] = fmaf(w, bfbits_to_f((unsigned short)(v.z & 0xffffu)), a8[4]);
        a8[5] = fmaf(w, bfbits_to_f((unsigned short)(v.z >> 16)),     a8[5]);
        a8[6] = fmaf(w, bfbits_to_f((unsigned short)(v.w & 0xffffu)), a8[6]);
        a8[7] = fmaf(w, bfbits_to_f((unsigned short)(v.w >> 16)),     a8[7]);
    }
    float4 o0 = {a8[0] * inv, a8[1] * inv, a8[2] * inv, a8[3] * inv};
    float4 o1 = {a8[4] * inv, a8[5] * inv, a8[6] * inv, a8[7] * inv};
    *(float4*)(out + (size_t)i * OUTF + lane * 8)     = o0;
    *(float4*)(out + (size_t)i * OUTF + lane * 8 + 4) = o1;
}

// ================= fallback path (f32, known-good) =================
__global__ __launch_bounds__(256) void gemm_f32(const float* __restrict__ A,
                                                const float* __restrict__ B,
                                                float* __restrict__ C) {
    __shared__ float As[16][68];
    __shared__ float Bs[16][64];
    const int tid = threadIdx.x;
    const int tx = tid & 15, ty = tid >> 4;
    const int i0 = blockIdx.y * 64;
    const int j0 = blockIdx.x * 64;
    const int ar = tid >> 2;
    const int ac = (tid & 3) << 2;
    const int bk = tid >> 4;
    const int bc = (tid & 15) << 2;
    float acc[4][4] = {};
    for (int k0 = 0; k0 < IN_DIM; k0 += 16) {
        const float4 av = *(const float4*)(A + (size_t)(i0 + ar) * IN_DIM + k0 + ac);
        const float4 bv = *(const float4*)(B + (size_t)(k0 + bk) * OUTF + j0 + bc);
        __syncthreads();
        As[ac + 0][ar] = av.x; As[ac + 1][ar] = av.y;
        As[ac + 2][ar] = av.z; As[ac + 3][ar] = av.w;
        *(float4*)&Bs[bk][bc] = bv;
        __syncthreads();
#pragma unroll
        for (int k = 0; k < 16; ++k) {
            const float4 a4 = *(const float4*)&As[k][ty << 2];
            const float4 b4 = *(const float4*)&Bs[k][tx << 2];
            const float am[4] = {a4.x, a4.y, a4.z, a4.w};
            const float bn[4] = {b4.x, b4.y, b4.z, b4.w};
#pragma unroll
            for (int m = 0; m < 4; ++m)
#pragma unroll
                for (int n = 0; n < 4; ++n)
                    acc[m][n] = fmaf(am[m], bn[n], acc[m][n]);
        }
    }
#pragma unroll
    for (int m = 0; m < 4; ++m) {
        float4 v = {acc[m][0], acc[m][1], acc[m][2], acc[m][3]};
        *(float4*)(C + (size_t)(i0 + (ty << 2) + m) * OUTF + j0 + (tx << 2)) = v;
    }
}

__global__ __launch_bounds__(512) void el_er_kernel(const float* __restrict__ g,
                                                    const float* __restrict__ a,
                                                    float* __restrict__ el,
                                                    float* __restrict__ er) {
    const int i = blockIdx.x;
    const int wid = threadIdx.x >> 6;
    const int lane = threadIdx.x & 63;
    const float v = g[(size_t)i * OUTF + wid * HID + lane];
    float pl = v * a[lane];
    float pr = v * a[HID + lane];
#pragma unroll
    for (int off = 1; off < 64; off <<= 1) {
        pl += __shfl_xor(pl, off);
        pr += __shfl_xor(pr, off);
    }
    if (lane == 0) {
        el[(size_t)i * HEADS + wid] = pl;
        er[(size_t)i * HEADS + wid] = pr;
    }
}

__global__ __launch_bounds__(512) void gat_attn_f32(const int* __restrict__ adj,
                                                    const float* __restrict__ g,
                                                    const float* __restrict__ el,
                                                    const float* __restrict__ er,
                                                    float* __restrict__ out) {
    const int i = blockIdx.x;
    const int tid = threadIdx.x;
    const int lane = tid & 63;
    const int wid = tid >> 6;

    __shared__ int   nbr[MAXD];
    __shared__ float p[HEADS][MAXD + 2];
    __shared__ float red[8][256];
    __shared__ float sinv[8];
    __shared__ int   wave_base[8];
    __shared__ int   s_deg;

    const int4* row = (const int4*)(adj + (size_t)i * N_NODES);
    const int4 w0 = row[tid * 2 + 0];
    const int4 w1 = row[tid * 2 + 1];
    uint32_t msk = 0;
    if (w0.x) msk |= 1u;   if (w0.y) msk |= 2u;
    if (w0.z) msk |= 4u;   if (w0.w) msk |= 8u;
    if (w1.x) msk |= 16u;  if (w1.y) msk |= 32u;
    if (w1.z) msk |= 64u;  if (w1.w) msk |= 128u;

    const int c = __popc(msk);
    int inc = c;
#pragma unroll
    for (int off = 1; off < 64; off <<= 1) {
        const int t = __shfl_up(inc, off);
        if (lane >= off) inc += t;
    }
    if (lane == 63) wave_base[wid] = inc;
    __syncthreads();
    if (tid == 0) {
        int run = 0;
#pragma unroll
        for (int w = 0; w < 8; ++w) { const int t = wave_base[w]; wave_base[w] = run; run += t; }
        s_deg = run;
    }
    __syncthreads();
    int pos = wave_base[wid] + inc - c;
#pragma unroll
    for (int b = 0; b < 8; ++b) {
        if (msk & (1u << b)) {
            if (pos < MAXD) nbr[pos] = tid * 8 + b;
            ++pos;
        }
    }
    __syncthreads();
    const int deg = min(s_deg, MAXD);

    const float eli = el[(size_t)i * HEADS + wid];
    float m = -1e30f;
    for (int j = lane; j < deg; j += 64) {
        float e = eli + er[(size_t)nbr[j] * HEADS + wid];
        e = (e >= 0.f) ? e : SLOPE * e;
        p[wid][j] = e;
        m = fmaxf(m, e);
    }
#pragma unroll
    for (int off = 1; off < 64; off <<= 1) m = fmaxf(m, __shfl_xor(m, off));
    float s = 0.f;
    for (int j = lane; j < deg; j += 64) {
        const float pe = __expf(p[wid][j] - m);
        p[wid][j] = pe;
        s += pe;
    }
#pragma unroll
    for (int off = 1; off < 64; off <<= 1) s += __shfl_xor(s, off);
    if (lane == 0) sinv[wid] = 1.f / s;
    __syncthreads();

    const int half = wid >> 2, jslot = wid & 3;
    const int head = half * 4 + (lane >> 4);
    const int f4 = (lane & 15) * 4;
    const float* gbase = g + (size_t)head * HID + f4;
    float4 acc = {0.f, 0.f, 0.f, 0.f};
#pragma unroll 4
    for (int j = jslot; j < deg; j += 4) {
        const int nj = nbr[j];
        const float w = p[head][j];
        const float4 v = *(const float4*)(gbase + (size_t)nj * OUTF);
        acc.x = fmaf(w, v.x, acc.x);
        acc.y = fmaf(w, v.y, acc.y);
        acc.z = fmaf(w, v.z, acc.z);
        acc.w = fmaf(w, v.w, acc.w);
    }
    *(float4*)&red[wid][(lane >> 4) * 64 + f4] = acc;
    __syncthreads();

    const int hf = tid >> 8, loc = tid & 255;
    const float v = red[hf * 4 + 0][loc] + red[hf * 4 + 1][loc] +
                    red[hf * 4 + 2][loc] + red[hf * 4 + 3][loc];
    out[(size_t)i * OUTF + tid] = v * sinv[tid >> 6];
}

extern "C" void kernel_launch(void* const* d_in, const int* in_sizes, int n_in,
                              void* d_out, int out_size, void* d_ws, size_t ws_size,
                              hipStream_t stream) {
    const float* h   = (const float*)d_in[0];
    const int*   adj = (const int*)d_in[1];
    const float* W   = (const float*)d_in[2];
    const float* a   = (const float*)d_in[3];
    float* out = (float*)d_out;
    char* ws = (char*)d_ws;

    // workspace layout (bytes)
    const size_t G_OFF   = 0;         // 8 MB region (bf16 path uses first 4 MB)
    const size_t EL_OFF  = 8388608;   // 128 KB
    const size_t ER_OFF  = 8519680;   // 128 KB
    const size_t BM_OFF  = 8650752;   // 2 MB
    const size_t HHI_OFF = 10747904;  // 4 MB
    const size_t WHI_OFF = 14942208;  // 512 KB
    const size_t WLO_OFF = 15466496;  // 512 KB
    const size_t NEED_FULL = 15990784;

    float* el = (float*)(ws + EL_OFF);
    float* er = (float*)(ws + ER_OFF);

    if (ws_size >= NEED_FULL) {
        unsigned short* gbf  = (unsigned short*)(ws + G_OFF);
        unsigned short* bm   = (unsigned short*)(ws + BM_OFF);
        unsigned short* hhi  = (unsigned short*)(ws + HHI_OFF);
        unsigned short* whiT = (unsigned short*)(ws + WHI_OFF);
        unsigned short* wloT = (unsigned short*)(ws + WLO_OFF);
        prep_conv<<<2304, 256, 0, stream>>>(h, hhi, W, whiT, wloT);
        gemm_pack<<<4608, 256, 0, stream>>>((const bf16_t*)hhi, (const bf16_t*)whiT,
                                            (const bf16_t*)wloT, a, gbf, el, er, adj, bm);
        gat_attn_wave<<<512, 512, 0, stream>>>((const unsigned long long*)bm, gbf, el, er, out);
    } else {
        float* g = (float*)(ws + G_OFF);
        gemm_f32<<<dim3(8, 64), 256, 0, stream>>>(h, W, g);
        el_er_kernel<<<N_NODES, 512, 0, stream>>>(g, a, el, er);
        gat_attn_f32<<<N_NODES, 512, 0, stream>>>(adj, g, el, er, out);
    }
}

// Round 7
// 43.913 us; speedup vs baseline: 2.4051x; 1.1177x over previous
//
#include <hip/hip_runtime.h>
#include <cstdint>
#include <cstddef>

#define N_NODES 4096
#define IN_DIM  512
#define HEADS   8
#define HID     64
#define OUTF    (HEADS * HID)   // 512
#define SLOPE   0.2f
#define MAXD    256             // fallback path cap
#define MAXD2   128             // wave-attn cap: deg ~ Binom(4096,0.01) mean 41 (13.6 sigma)

typedef __bf16 bf16_t;
typedef __attribute__((ext_vector_type(8))) __bf16 bf16x8;
typedef __attribute__((ext_vector_type(4))) float    f32x4;

#define GLD16(gp, lp)                                                                  \
    __builtin_amdgcn_global_load_lds((const __attribute__((address_space(1))) void*)(gp), \
                                     (__attribute__((address_space(3))) void*)(lp), 16, 0, 0)

__device__ __forceinline__ unsigned short to_bf16_u(float x) {
    uint32_t u = __builtin_bit_cast(uint32_t, x);
    u += 0x7fffu + ((u >> 16) & 1u);
    return (unsigned short)(u >> 16);
}
__device__ __forceinline__ float bfbits_to_f(unsigned short b) {
    uint32_t u = ((uint32_t)b) << 16;
    return __builtin_bit_cast(float, u);
}

// ---------------- prep_conv: h -> bf16 | W -> W_hiT/W_loT ----------------
__global__ __launch_bounds__(256) void prep_conv(const float* __restrict__ h,
                                                 unsigned short* __restrict__ hhi,
                                                 const float* __restrict__ W,
                                                 unsigned short* __restrict__ whiT,
                                                 unsigned short* __restrict__ wloT) {
    const int b = blockIdx.x;
    const int tid = threadIdx.x;
    if (b < 2048) {
        const int t = b * 256 + tid;                       // 0 .. 524287
        const float4 v = ((const float4*)h)[t];
        ushort4 hi;
        hi.x = to_bf16_u(v.x); hi.y = to_bf16_u(v.y);
        hi.z = to_bf16_u(v.z); hi.w = to_bf16_u(v.w);
        ((ushort4*)hhi)[t] = hi;
    } else {
        const int idx = (b - 2048) * 256 + tid;            // 0 .. 65535
        const int c   = idx & 511;
        const int kq  = (idx >> 9) * 4;                    // 0,4,..,508
        ushort4 hv, lv;
        float w0 = W[(size_t)(kq + 0) * OUTF + c];
        float w1 = W[(size_t)(kq + 1) * OUTF + c];
        float w2 = W[(size_t)(kq + 2) * OUTF + c];
        float w3 = W[(size_t)(kq + 3) * OUTF + c];
        hv.x = to_bf16_u(w0); lv.x = to_bf16_u(w0 - bfbits_to_f(hv.x));
        hv.y = to_bf16_u(w1); lv.y = to_bf16_u(w1 - bfbits_to_f(hv.y));
        hv.z = to_bf16_u(w2); lv.z = to_bf16_u(w2 - bfbits_to_f(hv.z));
        hv.w = to_bf16_u(w3); lv.w = to_bf16_u(w3 - bfbits_to_f(hv.w));
        *(ushort4*)&whiT[(size_t)c * IN_DIM + kq] = hv;
        *(ushort4*)&wloT[(size_t)c * IN_DIM + kq] = lv;
    }
}

// ---------------- fused gemm + pack_adj ----------------
// blocks [0,512): MFMA GEMM g(bf16) = h_hi @ (W_hi + W_lo), fused el/er.
//   64x64 tile, BK=64 (8 iters), 4 waves (2x2), wave tile 32x32.
//   XOR chunk swizzle c^(row&7) on both stage-source and frag-read.
// blocks [512,4608): adj int32 -> bitmask stream, overlapped with GEMM.
__global__ __launch_bounds__(256) void gemm_pack(const bf16_t* __restrict__ Ahi,
                                                 const bf16_t* __restrict__ BhiT,
                                                 const bf16_t* __restrict__ BloT,
                                                 const float* __restrict__ a,
                                                 unsigned short* __restrict__ Gb,
                                                 float* __restrict__ el,
                                                 float* __restrict__ er,
                                                 const int* __restrict__ adj,
                                                 unsigned short* __restrict__ bm16) {
    __shared__ bf16_t As[2][64 * 64];   // 8 KB each
    __shared__ bf16_t Bh[2][64 * 64];
    __shared__ bf16_t Bl[2][64 * 64];
    __shared__ float  elp[2][64], erp[2][64];

    const int tid = threadIdx.x;

    if (blockIdx.x >= 512) {            // ---- pack_adj part ----
        const int t = (blockIdx.x - 512) * 256 + tid;      // 0 .. 1048575
        const int4* src = (const int4*)adj + (size_t)t * 4;
        const int4 v0 = src[0], v1 = src[1], v2 = src[2], v3 = src[3];
        uint32_t m = 0;
        m |= (v0.x != 0) ? 1u << 0 : 0;  m |= (v0.y != 0) ? 1u << 1 : 0;
        m |= (v0.z != 0) ? 1u << 2 : 0;  m |= (v0.w != 0) ? 1u << 3 : 0;
        m |= (v1.x != 0) ? 1u << 4 : 0;  m |= (v1.y != 0) ? 1u << 5 : 0;
        m |= (v1.z != 0) ? 1u << 6 : 0;  m |= (v1.w != 0) ? 1u << 7 : 0;
        m |= (v2.x != 0) ? 1u << 8 : 0;  m |= (v2.y != 0) ? 1u << 9 : 0;
        m |= (v2.z != 0) ? 1u << 10 : 0; m |= (v2.w != 0) ? 1u << 11 : 0;
        m |= (v3.x != 0) ? 1u << 12 : 0; m |= (v3.y != 0) ? 1u << 13 : 0;
        m |= (v3.z != 0) ? 1u << 14 : 0; m |= (v3.w != 0) ? 1u << 15 : 0;
        bm16[t] = (unsigned short)m;
        return;
    }

    // ---- GEMM part ----
    const int wid = tid >> 6;
    const int lane = tid & 63;
    const int head = blockIdx.x & 7;
    const int i0 = (blockIdx.x >> 3) * 64;
    const int j0 = head * 64;
    const int l15 = lane & 15, kq = lane >> 4;

    // staging: per GLD16 a wave covers 8 rows x 8 chunks (16B each).
    // lane -> row sr0 = wid*16 + (lane>>3), chunk (lane&7) ^ (sr0&7).
    // ((sr0+8)&7) == (sr0&7), so the +8-row GLD16 keeps the same swizzle.
    const int sr0 = wid * 16 + (lane >> 3);
    const int sc  = (lane & 7) ^ (sr0 & 7);
    const size_t aoff = (size_t)(i0 + sr0) * IN_DIM + sc * 8;
    const size_t boff = (size_t)(j0 + sr0) * IN_DIM + sc * 8;
    const int ld0 = wid * 1024 + lane * 8;   // linear LDS dest (elements)

    // fragment read offsets: chunk cg = ks*4+kq of row, stored at cg^(row&7)
    const int wm = wid >> 1, wn = wid & 1;
    int aro[2][2], bro[2][2];
#pragma unroll
    for (int m = 0; m < 2; ++m) {
        const int row = wm * 32 + m * 16 + l15;
#pragma unroll
        for (int ks = 0; ks < 2; ++ks)
            aro[m][ks] = row * 64 + (((ks * 4 + kq) ^ (row & 7)) * 8);
    }
#pragma unroll
    for (int n = 0; n < 2; ++n) {
        const int col = wn * 32 + n * 16 + l15;
#pragma unroll
        for (int ks = 0; ks < 2; ++ks)
            bro[n][ks] = col * 64 + (((ks * 4 + kq) ^ (col & 7)) * 8);
    }

    f32x4 acc[2][2] = {};

    auto stage = [&](int buf, int t) {
        const size_t k0 = (size_t)t * 64;
        GLD16(Ahi  + aoff + k0,                       &As[buf][ld0]);
        GLD16(Ahi  + aoff + (size_t)8 * IN_DIM + k0,  &As[buf][ld0 + 512]);
        GLD16(BhiT + boff + k0,                       &Bh[buf][ld0]);
        GLD16(BhiT + boff + (size_t)8 * IN_DIM + k0,  &Bh[buf][ld0 + 512]);
        GLD16(BloT + boff + k0,                       &Bl[buf][ld0]);
        GLD16(BloT + boff + (size_t)8 * IN_DIM + k0,  &Bl[buf][ld0 + 512]);
    };

    stage(0, 0);
    for (int t = 0; t < 8; ++t) {
        const int cur = t & 1;
        if (t < 7) {
            stage(cur ^ 1, t + 1);
            asm volatile("s_waitcnt vmcnt(6)" ::: "memory");  // prev stage's 6 done
        } else {
            asm volatile("s_waitcnt vmcnt(0)" ::: "memory");
        }
        __builtin_amdgcn_s_barrier();
        asm volatile("" ::: "memory");

        bf16x8 af[2][2], bh2[2][2], bl2[2][2];
#pragma unroll
        for (int m = 0; m < 2; ++m)
#pragma unroll
            for (int ks = 0; ks < 2; ++ks) af[m][ks] = *(const bf16x8*)&As[cur][aro[m][ks]];
#pragma unroll
        for (int n = 0; n < 2; ++n)
#pragma unroll
            for (int ks = 0; ks < 2; ++ks) {
                bh2[n][ks] = *(const bf16x8*)&Bh[cur][bro[n][ks]];
                bl2[n][ks] = *(const bf16x8*)&Bl[cur][bro[n][ks]];
            }
#pragma unroll
        for (int ks = 0; ks < 2; ++ks)
#pragma unroll
            for (int m = 0; m < 2; ++m)
#pragma unroll
                for (int n = 0; n < 2; ++n) {
                    acc[m][n] = __builtin_amdgcn_mfma_f32_16x16x32_bf16(af[m][ks], bh2[n][ks], acc[m][n], 0, 0, 0);
                    acc[m][n] = __builtin_amdgcn_mfma_f32_16x16x32_bf16(af[m][ks], bl2[n][ks], acc[m][n], 0, 0, 0);
                }

        __builtin_amdgcn_s_barrier();
        asm volatile("" ::: "memory");
    }

    // ---- write g bf16 (C/D layout: col=lane&15, row=(lane>>4)*4+reg) ----
#pragma unroll
    for (int m = 0; m < 2; ++m)
#pragma unroll
        for (int n = 0; n < 2; ++n) {
            const int col = j0 + wn * 32 + n * 16 + l15;
#pragma unroll
            for (int q = 0; q < 4; ++q) {
                const int row = i0 + wm * 32 + m * 16 + kq * 4 + q;
                Gb[(size_t)row * OUTF + col] = to_bf16_u(acc[m][n][q]);
            }
        }

    // ---- fused el/er: wave covers 32 cols; cross-wave-pair reduce via LDS ----
    float al[2], arr[2];
#pragma unroll
    for (int n = 0; n < 2; ++n) {
        al[n]  = a[wn * 32 + n * 16 + l15];
        arr[n] = a[64 + wn * 32 + n * 16 + l15];
    }
#pragma unroll
    for (int m = 0; m < 2; ++m)
#pragma unroll
        for (int q = 0; q < 4; ++q) {
            float pe = 0.f, pr = 0.f;
#pragma unroll
            for (int n = 0; n < 2; ++n) {
                const float v = acc[m][n][q];
                pe = fmaf(v, al[n], pe);
                pr = fmaf(v, arr[n], pr);
            }
#pragma unroll
            for (int off = 1; off < 16; off <<= 1) {
                pe += __shfl_xor(pe, off);
                pr += __shfl_xor(pr, off);
            }
            if (l15 == 0) {
                const int lrow = wm * 32 + m * 16 + kq * 4 + q;
                elp[wn][lrow] = pe;
                erp[wn][lrow] = pr;
            }
        }
    __syncthreads();
    if (tid < 64) {
        el[(size_t)(i0 + tid) * HEADS + head] = elp[0][tid] + elp[1][tid];
        er[(size_t)(i0 + tid) * HEADS + head] = erp[0][tid] + erp[1][tid];
    }
}

// ---------------- attn: 2 waves per row ----------------
// 1024 blocks x 512 thr (8 waves): wave pair (sub=0/1) owns row r = wid>>1.
// Phase A (parallel, no cross-wave dep): each wave compacts its OWN nbr copy
// and computes softmax for its 4-head half. One barrier. Phase B: j-loop split
// even/odd across the pair (serial chain deg->deg/2), full-row 1KB coalesced
// bf16 gather. Partials combine via LDS.
__global__ __launch_bounds__(512) void gat_attn_wave(const unsigned long long* __restrict__ bm64,
                                                     const unsigned short* __restrict__ Gb,
                                                     const float* __restrict__ el,
                                                     const float* __restrict__ er,
                                                     float* __restrict__ out) {
    __shared__ int   nbr[4][2][MAXD2];
    __shared__ float pw[4][8][MAXD2 + 8];
    __shared__ float red[4][2][OUTF];
    __shared__ float sinv[4][8];
    const int tid = threadIdx.x;
    const int lane = tid & 63;
    const int wid = tid >> 6;
    const int r = wid >> 1, sub = wid & 1;
    const int i = blockIdx.x * 4 + r;

    // ---- compaction (each wave builds its own identical copy) ----
    unsigned long long q = bm64[(size_t)i * 64 + lane];
    const int c = __popcll(q);
    int inc = c;
#pragma unroll
    for (int off = 1; off < 64; off <<= 1) {
        const int t = __shfl_up(inc, off);
        if (lane >= off) inc += t;
    }
    const int deg = min(__shfl(inc, 63), MAXD2);
    int pos = inc - c;
    while (q) {
        const int b = __builtin_ctzll(q);
        q &= q - 1;
        if (pos < MAXD2) nbr[r][sub][pos] = lane * 64 + b;
        ++pos;
    }
    asm volatile("s_waitcnt lgkmcnt(0)" ::: "memory");
    __builtin_amdgcn_wave_barrier();

    // ---- softmax for this wave's 4-head half ----
    const float4 el4 = *(const float4*)(el + (size_t)i * 8 + sub * 4);
    float mx[4] = {-1e30f, -1e30f, -1e30f, -1e30f};
    for (int j = lane; j < deg; j += 64) {
        const int nj = nbr[r][sub][j];
        const float4 er4 = *(const float4*)(er + (size_t)nj * 8 + sub * 4);
        float e[4] = {el4.x + er4.x, el4.y + er4.y, el4.z + er4.z, el4.w + er4.w};
#pragma unroll
        for (int hh = 0; hh < 4; ++hh) {
            e[hh] = (e[hh] >= 0.f) ? e[hh] : SLOPE * e[hh];
            pw[r][sub * 4 + hh][j] = e[hh];
            mx[hh] = fmaxf(mx[hh], e[hh]);
        }
    }
#pragma unroll
    for (int off = 1; off < 64; off <<= 1)
#pragma unroll
        for (int hh = 0; hh < 4; ++hh) mx[hh] = fmaxf(mx[hh], __shfl_xor(mx[hh], off));

    float s4[4] = {};
    for (int j = lane; j < deg; j += 64) {
#pragma unroll
        for (int hh = 0; hh < 4; ++hh) {
            const float pe = __expf(pw[r][sub * 4 + hh][j] - mx[hh]);
            pw[r][sub * 4 + hh][j] = pe;
            s4[hh] += pe;
        }
    }
#pragma unroll
    for (int off = 1; off < 64; off <<= 1)
#pragma unroll
        for (int hh = 0; hh < 4; ++hh) s4[hh] += __shfl_xor(s4[hh], off);
    if (lane == 0) {
#pragma unroll
        for (int hh = 0; hh < 4; ++hh) sinv[r][sub * 4 + hh] = 1.f / s4[hh];
    }
    __syncthreads();   // pw + sinv complete across the block

    // ---- gather: j = sub, sub+2, ...; lane covers feats lane*8..+7 ----
    const int myhead = lane >> 3;
    float a8[8] = {};
    const unsigned short* gl = Gb + lane * 8;
#pragma unroll 4
    for (int j = sub; j < deg; j += 2) {
        const int nj = nbr[r][sub][j];
        const float w = pw[r][myhead][j];
        const uint4 v = *(const uint4*)(gl + (size_t)nj * OUTF);
        a8[0] = fmaf(w, bfbits_to_f((unsigned short)(v.x & 0xffffu)), a8[0]);
        a8[1] = fmaf(w, bfbits_to_f((unsigned short)(v.x >> 16)),     a8[1]);
        a8[2] = fmaf(w, bfbits_to_f((unsigned short)(v.y & 0xffffu)), a8[2]);
        a8[3] = fmaf(w, bfbits_to_f((unsigned short)(v.y >> 16)),     a8[3]);
        a8[4] = fmaf(w, bfbits_to_f((unsigned short)(v.z & 0xffffu)), a8[4]);
        a8[5] = fmaf(w, bfbits_to_f((unsigned short)(v.z >> 16)),     a8[5]);
        a8[6] = fmaf(w, bfbits_to_f((unsigned short)(v.w & 0xffffu)), a8[6]);
        a8[7] = fmaf(w, bfbits_to_f((unsigned short)(v.w >> 16)),     a8[7]);
    }
    float4 lo = {a8[0], a8[1], a8[2], a8[3]};
    float4 hi = {a8[4], a8[5], a8[6], a8[7]};
    *(float4*)&red[r][sub][lane * 8 + 0] = lo;
    *(float4*)&red[r][sub][lane * 8 + 4] = hi;
    __syncthreads();

    // ---- combine partials + normalize + store (coalesced) ----
#pragma unroll
    for (int rr = 0; rr < 4; ++rr) {
        const float v = red[rr][0][tid] + red[rr][1][tid];
        out[(size_t)(blockIdx.x * 4 + rr) * OUTF + tid] = v * sinv[rr][tid >> 6];
    }
}

// ================= fallback path (f32, known-good) =================
__global__ __launch_bounds__(256) void gemm_f32(const float* __restrict__ A,
                                                const float* __restrict__ B,
                                                float* __restrict__ C) {
    __shared__ float As[16][68];
    __shared__ float Bs[16][64];
    const int tid = threadIdx.x;
    const int tx = tid & 15, ty = tid >> 4;
    const int i0 = blockIdx.y * 64;
    const int j0 = blockIdx.x * 64;
    const int ar = tid >> 2;
    const int ac = (tid & 3) << 2;
    const int bk = tid >> 4;
    const int bc = (tid & 15) << 2;
    float acc[4][4] = {};
    for (int k0 = 0; k0 < IN_DIM; k0 += 16) {
        const float4 av = *(const float4*)(A + (size_t)(i0 + ar) * IN_DIM + k0 + ac);
        const float4 bv = *(const float4*)(B + (size_t)(k0 + bk) * OUTF + j0 + bc);
        __syncthreads();
        As[ac + 0][ar] = av.x; As[ac + 1][ar] = av.y;
        As[ac + 2][ar] = av.z; As[ac + 3][ar] = av.w;
        *(float4*)&Bs[bk][bc] = bv;
        __syncthreads();
#pragma unroll
        for (int k = 0; k < 16; ++k) {
            const float4 a4 = *(const float4*)&As[k][ty << 2];
            const float4 b4 = *(const float4*)&Bs[k][tx << 2];
            const float am[4] = {a4.x, a4.y, a4.z, a4.w};
            const float bn[4] = {b4.x, b4.y, b4.z, b4.w};
#pragma unroll
            for (int m = 0; m < 4; ++m)
#pragma unroll
                for (int n = 0; n < 4; ++n)
                    acc[m][n] = fmaf(am[m], bn[n], acc[m][n]);
        }
    }
#pragma unroll
    for (int m = 0; m < 4; ++m) {
        float4 v = {acc[m][0], acc[m][1], acc[m][2], acc[m][3]};
        *(float4*)(C + (size_t)(i0 + (ty << 2) + m) * OUTF + j0 + (tx << 2)) = v;
    }
}

__global__ __launch_bounds__(512) void el_er_kernel(const float* __restrict__ g,
                                                    const float* __restrict__ a,
                                                    float* __restrict__ el,
                                                    float* __restrict__ er) {
    const int i = blockIdx.x;
    const int wid = threadIdx.x >> 6;
    const int lane = threadIdx.x & 63;
    const float v = g[(size_t)i * OUTF + wid * HID + lane];
    float pl = v * a[lane];
    float pr = v * a[HID + lane];
#pragma unroll
    for (int off = 1; off < 64; off <<= 1) {
        pl += __shfl_xor(pl, off);
        pr += __shfl_xor(pr, off);
    }
    if (lane == 0) {
        el[(size_t)i * HEADS + wid] = pl;
        er[(size_t)i * HEADS + wid] = pr;
    }
}

__global__ __launch_bounds__(512) void gat_attn_f32(const int* __restrict__ adj,
                                                    const float* __restrict__ g,
                                                    const float* __restrict__ el,
                                                    const float* __restrict__ er,
                                                    float* __restrict__ out) {
    const int i = blockIdx.x;
    const int tid = threadIdx.x;
    const int lane = tid & 63;
    const int wid = tid >> 6;

    __shared__ int   nbr[MAXD];
    __shared__ float p[HEADS][MAXD + 2];
    __shared__ float red[8][256];
    __shared__ float sinv[8];
    __shared__ int   wave_base[8];
    __shared__ int   s_deg;

    const int4* row = (const int4*)(adj + (size_t)i * N_NODES);
    const int4 w0 = row[tid * 2 + 0];
    const int4 w1 = row[tid * 2 + 1];
    uint32_t msk = 0;
    if (w0.x) msk |= 1u;   if (w0.y) msk |= 2u;
    if (w0.z) msk |= 4u;   if (w0.w) msk |= 8u;
    if (w1.x) msk |= 16u;  if (w1.y) msk |= 32u;
    if (w1.z) msk |= 64u;  if (w1.w) msk |= 128u;

    const int c = __popc(msk);
    int inc = c;
#pragma unroll
    for (int off = 1; off < 64; off <<= 1) {
        const int t = __shfl_up(inc, off);
        if (lane >= off) inc += t;
    }
    if (lane == 63) wave_base[wid] = inc;
    __syncthreads();
    if (tid == 0) {
        int run = 0;
#pragma unroll
        for (int w = 0; w < 8; ++w) { const int t = wave_base[w]; wave_base[w] = run; run += t; }
        s_deg = run;
    }
    __syncthreads();
    int pos = wave_base[wid] + inc - c;
#pragma unroll
    for (int b = 0; b < 8; ++b) {
        if (msk & (1u << b)) {
            if (pos < MAXD) nbr[pos] = tid * 8 + b;
            ++pos;
        }
    }
    __syncthreads();
    const int deg = min(s_deg, MAXD);

    const float eli = el[(size_t)i * HEADS + wid];
    float m = -1e30f;
    for (int j = lane; j < deg; j += 64) {
        float e = eli + er[(size_t)nbr[j] * HEADS + wid];
        e = (e >= 0.f) ? e : SLOPE * e;
        p[wid][j] = e;
        m = fmaxf(m, e);
    }
#pragma unroll
    for (int off = 1; off < 64; off <<= 1) m = fmaxf(m, __shfl_xor(m, off));
    float s = 0.f;
    for (int j = lane; j < deg; j += 64) {
        const float pe = __expf(p[wid][j] - m);
        p[wid][j] = pe;
        s += pe;
    }
#pragma unroll
    for (int off = 1; off < 64; off <<= 1) s += __shfl_xor(s, off);
    if (lane == 0) sinv[wid] = 1.f / s;
    __syncthreads();

    const int half = wid >> 2, jslot = wid & 3;
    const int head = half * 4 + (lane >> 4);
    const int f4 = (lane & 15) * 4;
    const float* gbase = g + (size_t)head * HID + f4;
    float4 acc = {0.f, 0.f, 0.f, 0.f};
#pragma unroll 4
    for (int j = jslot; j < deg; j += 4) {
        const int nj = nbr[j];
        const float w = p[head][j];
        const float4 v = *(const float4*)(gbase + (size_t)nj * OUTF);
        acc.x = fmaf(w, v.x, acc.x);
        acc.y = fmaf(w, v.y, acc.y);
        acc.z = fmaf(w, v.z, acc.z);
        acc.w = fmaf(w, v.w, acc.w);
    }
    *(float4*)&red[wid][(lane >> 4) * 64 + f4] = acc;
    __syncthreads();

    const int hf = tid >> 8, loc = tid & 255;
    const float v = red[hf * 4 + 0][loc] + red[hf * 4 + 1][loc] +
                    red[hf * 4 + 2][loc] + red[hf * 4 + 3][loc];
    out[(size_t)i * OUTF + tid] = v * sinv[tid >> 6];
}

extern "C" void kernel_launch(void* const* d_in, const int* in_sizes, int n_in,
                              void* d_out, int out_size, void* d_ws, size_t ws_size,
                              hipStream_t stream) {
    const float* h   = (const float*)d_in[0];
    const int*   adj = (const int*)d_in[1];
    const float* W   = (const float*)d_in[2];
    const float* a   = (const float*)d_in[3];
    float* out = (float*)d_out;
    char* ws = (char*)d_ws;

    // workspace layout (bytes)
    const size_t G_OFF   = 0;         // 8 MB region (bf16 path uses first 4 MB)
    const size_t EL_OFF  = 8388608;   // 128 KB
    const size_t ER_OFF  = 8519680;   // 128 KB
    const size_t BM_OFF  = 8650752;   // 2 MB
    const size_t HHI_OFF = 10747904;  // 4 MB
    const size_t WHI_OFF = 14942208;  // 512 KB
    const size_t WLO_OFF = 15466496;  // 512 KB
    const size_t NEED_FULL = 15990784;

    float* el = (float*)(ws + EL_OFF);
    float* er = (float*)(ws + ER_OFF);

    if (ws_size >= NEED_FULL) {
        unsigned short* gbf  = (unsigned short*)(ws + G_OFF);
        unsigned short* bm   = (unsigned short*)(ws + BM_OFF);
        unsigned short* hhi  = (unsigned short*)(ws + HHI_OFF);
        unsigned short* whiT = (unsigned short*)(ws + WHI_OFF);
        unsigned short* wloT = (unsigned short*)(ws + WLO_OFF);
        prep_conv<<<2304, 256, 0, stream>>>(h, hhi, W, whiT, wloT);
        gemm_pack<<<4608, 256, 0, stream>>>((const bf16_t*)hhi, (const bf16_t*)whiT,
                                            (const bf16_t*)wloT, a, gbf, el, er, adj, bm);
        gat_attn_wave<<<1024, 512, 0, stream>>>((const unsigned long long*)bm, gbf, el, er, out);
    } else {
        float* g = (float*)(ws + G_OFF);
        gemm_f32<<<dim3(8, 64), 256, 0, stream>>>(h, W, g);
        el_er_kernel<<<N_NODES, 512, 0, stream>>>(g, a, el, er);
        gat_attn_f32<<<N_NODES, 512, 0, stream>>>(adj, g, el, er, out);
    }
}

// Round 8
// 42.903 us; speedup vs baseline: 2.4618x; 1.0235x over previous
//
#include <hip/hip_runtime.h>
#include <cstdint>
#include <cstddef>

#define N_NODES 4096
#define IN_DIM  512
#define HEADS   8
#define HID     64
#define OUTF    (HEADS * HID)   // 512
#define SLOPE   0.2f
#define MAXD    256             // fallback path cap
#define MAXD2   128             // wave-attn cap: deg ~ Binom(4096,0.01) mean 41 (13.6 sigma)

typedef __bf16 bf16_t;
typedef __attribute__((ext_vector_type(8))) __bf16 bf16x8;
typedef __attribute__((ext_vector_type(4))) float    f32x4;

#define GLD16(gp, lp)                                                                  \
    __builtin_amdgcn_global_load_lds((const __attribute__((address_space(1))) void*)(gp), \
                                     (__attribute__((address_space(3))) void*)(lp), 16, 0, 0)

__device__ __forceinline__ unsigned short to_bf16_u(float x) {
    uint32_t u = __builtin_bit_cast(uint32_t, x);
    u += 0x7fffu + ((u >> 16) & 1u);
    return (unsigned short)(u >> 16);
}
__device__ __forceinline__ float bfbits_to_f(unsigned short b) {
    uint32_t u = ((uint32_t)b) << 16;
    return __builtin_bit_cast(float, u);
}

// ---------------- streampack: pack_adj | W -> W_hiT/W_loT (NO LDS!) ----------------
// blocks [0,4096): adj int32 -> bitmask (64 MB stream at FULL occupancy).
// blocks [4096,4352): W split-transpose (1 MB read).
__global__ __launch_bounds__(256) void streampack(const int* __restrict__ adj,
                                                  unsigned short* __restrict__ bm16,
                                                  const float* __restrict__ W,
                                                  unsigned short* __restrict__ whiT,
                                                  unsigned short* __restrict__ wloT) {
    const int b = blockIdx.x;
    const int tid = threadIdx.x;
    if (b < 4096) {
        const int t = b * 256 + tid;                       // 0 .. 1048575
        const int4* src = (const int4*)adj + (size_t)t * 4;
        const int4 v0 = src[0], v1 = src[1], v2 = src[2], v3 = src[3];
        uint32_t m = 0;
        m |= (v0.x != 0) ? 1u << 0 : 0;  m |= (v0.y != 0) ? 1u << 1 : 0;
        m |= (v0.z != 0) ? 1u << 2 : 0;  m |= (v0.w != 0) ? 1u << 3 : 0;
        m |= (v1.x != 0) ? 1u << 4 : 0;  m |= (v1.y != 0) ? 1u << 5 : 0;
        m |= (v1.z != 0) ? 1u << 6 : 0;  m |= (v1.w != 0) ? 1u << 7 : 0;
        m |= (v2.x != 0) ? 1u << 8 : 0;  m |= (v2.y != 0) ? 1u << 9 : 0;
        m |= (v2.z != 0) ? 1u << 10 : 0; m |= (v2.w != 0) ? 1u << 11 : 0;
        m |= (v3.x != 0) ? 1u << 12 : 0; m |= (v3.y != 0) ? 1u << 13 : 0;
        m |= (v3.z != 0) ? 1u << 14 : 0; m |= (v3.w != 0) ? 1u << 15 : 0;
        bm16[t] = (unsigned short)m;
    } else {
        const int idx = (b - 4096) * 256 + tid;            // 0 .. 65535
        const int c   = idx & 511;
        const int kq  = (idx >> 9) * 4;                    // 0,4,..,508
        ushort4 hv, lv;
        float w0 = W[(size_t)(kq + 0) * OUTF + c];
        float w1 = W[(size_t)(kq + 1) * OUTF + c];
        float w2 = W[(size_t)(kq + 2) * OUTF + c];
        float w3 = W[(size_t)(kq + 3) * OUTF + c];
        hv.x = to_bf16_u(w0); lv.x = to_bf16_u(w0 - bfbits_to_f(hv.x));
        hv.y = to_bf16_u(w1); lv.y = to_bf16_u(w1 - bfbits_to_f(hv.y));
        hv.z = to_bf16_u(w2); lv.z = to_bf16_u(w2 - bfbits_to_f(hv.z));
        hv.w = to_bf16_u(w3); lv.w = to_bf16_u(w3 - bfbits_to_f(hv.w));
        *(ushort4*)&whiT[(size_t)c * IN_DIM + kq] = hv;
        *(ushort4*)&wloT[(size_t)c * IN_DIM + kq] = lv;
    }
}

// ---------------- MFMA GEMM, A staged directly from f32 h ----------------
// g(bf16) = bf16(h) @ (W_hi + W_lo), fused el/er. 64x64 tile, BK=64 (8 iters),
// 4 waves (2x2), wave tile 32x32. bid = head*64 + rowtile (head-major): since
// 64%8==0, rowtile r lands on XCD r%8 for EVERY head -> A tile HBM-fetched once,
// then L2-reused by all 8 head-blocks on that XCD.
// A in LDS as f32 [row][64k], chunk(16B=4f32) swizzle c^(row&15) both sides.
// B (bf16) chunk(16B=8bf16) swizzle c^(row&7) both sides (as R7).
__global__ __launch_bounds__(256) void gemm_f32A(const float* __restrict__ Hf,
                                                 const bf16_t* __restrict__ BhiT,
                                                 const bf16_t* __restrict__ BloT,
                                                 const float* __restrict__ a,
                                                 unsigned short* __restrict__ Gb,
                                                 float* __restrict__ el,
                                                 float* __restrict__ er) {
    __shared__ float  As[2][64 * 64];   // 16 KB each
    __shared__ bf16_t Bh[2][64 * 64];   // 8 KB each
    __shared__ bf16_t Bl[2][64 * 64];
    __shared__ float  elp[2][64], erp[2][64];

    const int tid = threadIdx.x;
    const int wid = tid >> 6;
    const int lane = tid & 63;
    const int head = blockIdx.x >> 6;         // head-major!
    const int i0 = (blockIdx.x & 63) * 64;
    const int j0 = head * 64;
    const int l15 = lane & 15, kq = lane >> 4;

    // ---- A staging: 4 GLD16/wave, call c4 covers rows wid*16+c4*4 .. +3 ----
    size_t aoff[4];
#pragma unroll
    for (int c4 = 0; c4 < 4; ++c4) {
        const int row = wid * 16 + c4 * 4 + (lane >> 4);   // lane>>4: row within quad
        const int sc = (lane & 15) ^ (row & 15);           // swizzled 16B chunk
        aoff[c4] = (size_t)(i0 + row) * IN_DIM + sc * 4;   // f32 elements
    }
    // ---- B staging: 2 GLD16/wave each for Bh, Bl ----
    const int sr0 = wid * 16 + (lane >> 3);
    const int scb = (lane & 7) ^ (sr0 & 7);
    const size_t boff = (size_t)(j0 + sr0) * IN_DIM + scb * 8;   // bf16 elements

    // ---- fragment read offsets ----
    const int wm = wid >> 1, wn = wid & 1;
    int aro[2][2][2], bro[2][2];
#pragma unroll
    for (int m = 0; m < 2; ++m) {
        const int row = wm * 32 + m * 16 + l15;
#pragma unroll
        for (int ks = 0; ks < 2; ++ks) {
            const int c0 = ks * 8 + kq * 2;                // 16B chunk of this frag's k0..3
            aro[m][ks][0] = row * 64 + ((c0 + 0) ^ (row & 15)) * 4;
            aro[m][ks][1] = row * 64 + ((c0 + 1) ^ (row & 15)) * 4;
        }
    }
#pragma unroll
    for (int n = 0; n < 2; ++n) {
        const int col = wn * 32 + n * 16 + l15;
#pragma unroll
        for (int ks = 0; ks < 2; ++ks)
            bro[n][ks] = col * 64 + (((ks * 4 + kq) ^ (col & 7)) * 8);
    }

    f32x4 acc[2][2] = {};

    auto stage = [&](int buf, int t) {
        const size_t k0 = (size_t)t * 64;
#pragma unroll
        for (int c4 = 0; c4 < 4; ++c4)
            GLD16(Hf + aoff[c4] + k0, &As[buf][(wid * 16 + c4 * 4) * 64]);
        GLD16(BhiT + boff + k0,                      &Bh[buf][(wid * 16) * 64]);
        GLD16(BhiT + boff + (size_t)8 * IN_DIM + k0, &Bh[buf][(wid * 16 + 8) * 64]);
        GLD16(BloT + boff + k0,                      &Bl[buf][(wid * 16) * 64]);
        GLD16(BloT + boff + (size_t)8 * IN_DIM + k0, &Bl[buf][(wid * 16 + 8) * 64]);
    };

    stage(0, 0);
    for (int t = 0; t < 8; ++t) {
        const int cur = t & 1;
        if (t < 7) {
            stage(cur ^ 1, t + 1);
            asm volatile("s_waitcnt vmcnt(8)" ::: "memory");   // cur buf's 8 done
        } else {
            asm volatile("s_waitcnt vmcnt(0)" ::: "memory");
        }
        __builtin_amdgcn_s_barrier();
        asm volatile("" ::: "memory");

        // A frags: 2x ds_read_b128 (f32x4) -> bf16x8 RNE convert in-reg
        bf16x8 af[2][2];
#pragma unroll
        for (int m = 0; m < 2; ++m)
#pragma unroll
            for (int ks = 0; ks < 2; ++ks) {
                const f32x4 lo4 = *(const f32x4*)&As[cur][aro[m][ks][0]];
                const f32x4 hi4 = *(const f32x4*)&As[cur][aro[m][ks][1]];
                bf16x8 v;
                v[0] = (bf16_t)lo4[0]; v[1] = (bf16_t)lo4[1];
                v[2] = (bf16_t)lo4[2]; v[3] = (bf16_t)lo4[3];
                v[4] = (bf16_t)hi4[0]; v[5] = (bf16_t)hi4[1];
                v[6] = (bf16_t)hi4[2]; v[7] = (bf16_t)hi4[3];
                af[m][ks] = v;
            }
        bf16x8 bh2[2][2], bl2[2][2];
#pragma unroll
        for (int n = 0; n < 2; ++n)
#pragma unroll
            for (int ks = 0; ks < 2; ++ks) {
                bh2[n][ks] = *(const bf16x8*)&Bh[cur][bro[n][ks]];
                bl2[n][ks] = *(const bf16x8*)&Bl[cur][bro[n][ks]];
            }
#pragma unroll
        for (int ks = 0; ks < 2; ++ks)
#pragma unroll
            for (int m = 0; m < 2; ++m)
#pragma unroll
                for (int n = 0; n < 2; ++n) {
                    acc[m][n] = __builtin_amdgcn_mfma_f32_16x16x32_bf16(af[m][ks], bh2[n][ks], acc[m][n], 0, 0, 0);
                    acc[m][n] = __builtin_amdgcn_mfma_f32_16x16x32_bf16(af[m][ks], bl2[n][ks], acc[m][n], 0, 0, 0);
                }

        __builtin_amdgcn_s_barrier();
        asm volatile("" ::: "memory");
    }

    // ---- write g bf16 (C/D layout: col=lane&15, row=(lane>>4)*4+reg) ----
#pragma unroll
    for (int m = 0; m < 2; ++m)
#pragma unroll
        for (int n = 0; n < 2; ++n) {
            const int col = j0 + wn * 32 + n * 16 + l15;
#pragma unroll
            for (int q = 0; q < 4; ++q) {
                const int row = i0 + wm * 32 + m * 16 + kq * 4 + q;
                Gb[(size_t)row * OUTF + col] = to_bf16_u(acc[m][n][q]);
            }
        }

    // ---- fused el/er ----
    float al[2], arr[2];
#pragma unroll
    for (int n = 0; n < 2; ++n) {
        al[n]  = a[wn * 32 + n * 16 + l15];
        arr[n] = a[64 + wn * 32 + n * 16 + l15];
    }
#pragma unroll
    for (int m = 0; m < 2; ++m)
#pragma unroll
        for (int q = 0; q < 4; ++q) {
            float pe = 0.f, pr = 0.f;
#pragma unroll
            for (int n = 0; n < 2; ++n) {
                const float v = acc[m][n][q];
                pe = fmaf(v, al[n], pe);
                pr = fmaf(v, arr[n], pr);
            }
#pragma unroll
            for (int off = 1; off < 16; off <<= 1) {
                pe += __shfl_xor(pe, off);
                pr += __shfl_xor(pr, off);
            }
            if (l15 == 0) {
                const int lrow = wm * 32 + m * 16 + kq * 4 + q;
                elp[wn][lrow] = pe;
                erp[wn][lrow] = pr;
            }
        }
    __syncthreads();
    if (tid < 64) {
        el[(size_t)(i0 + tid) * HEADS + head] = elp[0][tid] + elp[1][tid];
        er[(size_t)(i0 + tid) * HEADS + head] = erp[0][tid] + erp[1][tid];
    }
}

// ---------------- attn: 2 waves per row (unchanged from R7) ----------------
__global__ __launch_bounds__(512) void gat_attn_wave(const unsigned long long* __restrict__ bm64,
                                                     const unsigned short* __restrict__ Gb,
                                                     const float* __restrict__ el,
                                                     const float* __restrict__ er,
                                                     float* __restrict__ out) {
    __shared__ int   nbr[4][2][MAXD2];
    __shared__ float pw[4][8][MAXD2 + 8];
    __shared__ float red[4][2][OUTF];
    __shared__ float sinv[4][8];
    const int tid = threadIdx.x;
    const int lane = tid & 63;
    const int wid = tid >> 6;
    const int r = wid >> 1, sub = wid & 1;
    const int i = blockIdx.x * 4 + r;

    unsigned long long q = bm64[(size_t)i * 64 + lane];
    const int c = __popcll(q);
    int inc = c;
#pragma unroll
    for (int off = 1; off < 64; off <<= 1) {
        const int t = __shfl_up(inc, off);
        if (lane >= off) inc += t;
    }
    const int deg = min(__shfl(inc, 63), MAXD2);
    int pos = inc - c;
    while (q) {
        const int b = __builtin_ctzll(q);
        q &= q - 1;
        if (pos < MAXD2) nbr[r][sub][pos] = lane * 64 + b;
        ++pos;
    }
    asm volatile("s_waitcnt lgkmcnt(0)" ::: "memory");
    __builtin_amdgcn_wave_barrier();

    const float4 el4 = *(const float4*)(el + (size_t)i * 8 + sub * 4);
    float mx[4] = {-1e30f, -1e30f, -1e30f, -1e30f};
    for (int j = lane; j < deg; j += 64) {
        const int nj = nbr[r][sub][j];
        const float4 er4 = *(const float4*)(er + (size_t)nj * 8 + sub * 4);
        float e[4] = {el4.x + er4.x, el4.y + er4.y, el4.z + er4.z, el4.w + er4.w};
#pragma unroll
        for (int hh = 0; hh < 4; ++hh) {
            e[hh] = (e[hh] >= 0.f) ? e[hh] : SLOPE * e[hh];
            pw[r][sub * 4 + hh][j] = e[hh];
            mx[hh] = fmaxf(mx[hh], e[hh]);
        }
    }
#pragma unroll
    for (int off = 1; off < 64; off <<= 1)
#pragma unroll
        for (int hh = 0; hh < 4; ++hh) mx[hh] = fmaxf(mx[hh], __shfl_xor(mx[hh], off));

    float s4[4] = {};
    for (int j = lane; j < deg; j += 64) {
#pragma unroll
        for (int hh = 0; hh < 4; ++hh) {
            const float pe = __expf(pw[r][sub * 4 + hh][j] - mx[hh]);
            pw[r][sub * 4 + hh][j] = pe;
            s4[hh] += pe;
        }
    }
#pragma unroll
    for (int off = 1; off < 64; off <<= 1)
#pragma unroll
        for (int hh = 0; hh < 4; ++hh) s4[hh] += __shfl_xor(s4[hh], off);
    if (lane == 0) {
#pragma unroll
        for (int hh = 0; hh < 4; ++hh) sinv[r][sub * 4 + hh] = 1.f / s4[hh];
    }
    __syncthreads();

    const int myhead = lane >> 3;
    float a8[8] = {};
    const unsigned short* gl = Gb + lane * 8;
#pragma unroll 4
    for (int j = sub; j < deg; j += 2) {
        const int nj = nbr[r][sub][j];
        const float w = pw[r][myhead][j];
        const uint4 v = *(const uint4*)(gl + (size_t)nj * OUTF);
        a8[0] = fmaf(w, bfbits_to_f((unsigned short)(v.x & 0xffffu)), a8[0]);
        a8[1] = fmaf(w, bfbits_to_f((unsigned short)(v.x >> 16)),     a8[1]);
        a8[2] = fmaf(w, bfbits_to_f((unsigned short)(v.y & 0xffffu)), a8[2]);
        a8[3] = fmaf(w, bfbits_to_f((unsigned short)(v.y >> 16)),     a8[3]);
        a8[4] = fmaf(w, bfbits_to_f((unsigned short)(v.z & 0xffffu)), a8[4]);
        a8[5] = fmaf(w, bfbits_to_f((unsigned short)(v.z >> 16)),     a8[5]);
        a8[6] = fmaf(w, bfbits_to_f((unsigned short)(v.w & 0xffffu)), a8[6]);
        a8[7] = fmaf(w, bfbits_to_f((unsigned short)(v.w >> 16)),     a8[7]);
    }
    float4 lo = {a8[0], a8[1], a8[2], a8[3]};
    float4 hi = {a8[4], a8[5], a8[6], a8[7]};
    *(float4*)&red[r][sub][lane * 8 + 0] = lo;
    *(float4*)&red[r][sub][lane * 8 + 4] = hi;
    __syncthreads();

#pragma unroll
    for (int rr = 0; rr < 4; ++rr) {
        const float v = red[rr][0][tid] + red[rr][1][tid];
        out[(size_t)(blockIdx.x * 4 + rr) * OUTF + tid] = v * sinv[rr][tid >> 6];
    }
}

// ================= fallback path (f32, known-good) =================
__global__ __launch_bounds__(256) void gemm_f32(const float* __restrict__ A,
                                                const float* __restrict__ B,
                                                float* __restrict__ C) {
    __shared__ float As[16][68];
    __shared__ float Bs[16][64];
    const int tid = threadIdx.x;
    const int tx = tid & 15, ty = tid >> 4;
    const int i0 = blockIdx.y * 64;
    const int j0 = blockIdx.x * 64;
    const int ar = tid >> 2;
    const int ac = (tid & 3) << 2;
    const int bk = tid >> 4;
    const int bc = (tid & 15) << 2;
    float acc[4][4] = {};
    for (int k0 = 0; k0 < IN_DIM; k0 += 16) {
        const float4 av = *(const float4*)(A + (size_t)(i0 + ar) * IN_DIM + k0 + ac);
        const float4 bv = *(const float4*)(B + (size_t)(k0 + bk) * OUTF + j0 + bc);
        __syncthreads();
        As[ac + 0][ar] = av.x; As[ac + 1][ar] = av.y;
        As[ac + 2][ar] = av.z; As[ac + 3][ar] = av.w;
        *(float4*)&Bs[bk][bc] = bv;
        __syncthreads();
#pragma unroll
        for (int k = 0; k < 16; ++k) {
            const float4 a4 = *(const float4*)&As[k][ty << 2];
            const float4 b4 = *(const float4*)&Bs[k][tx << 2];
            const float am[4] = {a4.x, a4.y, a4.z, a4.w};
            const float bn[4] = {b4.x, b4.y, b4.z, b4.w};
#pragma unroll
            for (int m = 0; m < 4; ++m)
#pragma unroll
                for (int n = 0; n < 4; ++n)
                    acc[m][n] = fmaf(am[m], bn[n], acc[m][n]);
        }
    }
#pragma unroll
    for (int m = 0; m < 4; ++m) {
        float4 v = {acc[m][0], acc[m][1], acc[m][2], acc[m][3]};
        *(float4*)(C + (size_t)(i0 + (ty << 2) + m) * OUTF + j0 + (tx << 2)) = v;
    }
}

__global__ __launch_bounds__(512) void el_er_kernel(const float* __restrict__ g,
                                                    const float* __restrict__ a,
                                                    float* __restrict__ el,
                                                    float* __restrict__ er) {
    const int i = blockIdx.x;
    const int wid = threadIdx.x >> 6;
    const int lane = threadIdx.x & 63;
    const float v = g[(size_t)i * OUTF + wid * HID + lane];
    float pl = v * a[lane];
    float pr = v * a[HID + lane];
#pragma unroll
    for (int off = 1; off < 64; off <<= 1) {
        pl += __shfl_xor(pl, off);
        pr += __shfl_xor(pr, off);
    }
    if (lane == 0) {
        el[(size_t)i * HEADS + wid] = pl;
        er[(size_t)i * HEADS + wid] = pr;
    }
}

__global__ __launch_bounds__(512) void gat_attn_f32(const int* __restrict__ adj,
                                                    const float* __restrict__ g,
                                                    const float* __restrict__ el,
                                                    const float* __restrict__ er,
                                                    float* __restrict__ out) {
    const int i = blockIdx.x;
    const int tid = threadIdx.x;
    const int lane = tid & 63;
    const int wid = tid >> 6;

    __shared__ int   nbr[MAXD];
    __shared__ float p[HEADS][MAXD + 2];
    __shared__ float red[8][256];
    __shared__ float sinv[8];
    __shared__ int   wave_base[8];
    __shared__ int   s_deg;

    const int4* row = (const int4*)(adj + (size_t)i * N_NODES);
    const int4 w0 = row[tid * 2 + 0];
    const int4 w1 = row[tid * 2 + 1];
    uint32_t msk = 0;
    if (w0.x) msk |= 1u;   if (w0.y) msk |= 2u;
    if (w0.z) msk |= 4u;   if (w0.w) msk |= 8u;
    if (w1.x) msk |= 16u;  if (w1.y) msk |= 32u;
    if (w1.z) msk |= 64u;  if (w1.w) msk |= 128u;

    const int c = __popc(msk);
    int inc = c;
#pragma unroll
    for (int off = 1; off < 64; off <<= 1) {
        const int t = __shfl_up(inc, off);
        if (lane >= off) inc += t;
    }
    if (lane == 63) wave_base[wid] = inc;
    __syncthreads();
    if (tid == 0) {
        int run = 0;
#pragma unroll
        for (int w = 0; w < 8; ++w) { const int t = wave_base[w]; wave_base[w] = run; run += t; }
        s_deg = run;
    }
    __syncthreads();
    int pos = wave_base[wid] + inc - c;
#pragma unroll
    for (int b = 0; b < 8; ++b) {
        if (msk & (1u << b)) {
            if (pos < MAXD) nbr[pos] = tid * 8 + b;
            ++pos;
        }
    }
    __syncthreads();
    const int deg = min(s_deg, MAXD);

    const float eli = el[(size_t)i * HEADS + wid];
    float m = -1e30f;
    for (int j = lane; j < deg; j += 64) {
        float e = eli + er[(size_t)nbr[j] * HEADS + wid];
        e = (e >= 0.f) ? e : SLOPE * e;
        p[wid][j] = e;
        m = fmaxf(m, e);
    }
#pragma unroll
    for (int off = 1; off < 64; off <<= 1) m = fmaxf(m, __shfl_xor(m, off));
    float s = 0.f;
    for (int j = lane; j < deg; j += 64) {
        const float pe = __expf(p[wid][j] - m);
        p[wid][j] = pe;
        s += pe;
    }
#pragma unroll
    for (int off = 1; off < 64; off <<= 1) s += __shfl_xor(s, off);
    if (lane == 0) sinv[wid] = 1.f / s;
    __syncthreads();

    const int half = wid >> 2, jslot = wid & 3;
    const int head = half * 4 + (lane >> 4);
    const int f4 = (lane & 15) * 4;
    const float* gbase = g + (size_t)head * HID + f4;
    float4 acc = {0.f, 0.f, 0.f, 0.f};
#pragma unroll 4
    for (int j = jslot; j < deg; j += 4) {
        const int nj = nbr[j];
        const float w = p[head][j];
        const float4 v = *(const float4*)(gbase + (size_t)nj * OUTF);
        acc.x = fmaf(w, v.x, acc.x);
        acc.y = fmaf(w, v.y, acc.y);
        acc.z = fmaf(w, v.z, acc.z);
        acc.w = fmaf(w, v.w, acc.w);
    }
    *(float4*)&red[wid][(lane >> 4) * 64 + f4] = acc;
    __syncthreads();

    const int hf = tid >> 8, loc = tid & 255;
    const float v = red[hf * 4 + 0][loc] + red[hf * 4 + 1][loc] +
                    red[hf * 4 + 2][loc] + red[hf * 4 + 3][loc];
    out[(size_t)i * OUTF + tid] = v * sinv[tid >> 6];
}

extern "C" void kernel_launch(void* const* d_in, const int* in_sizes, int n_in,
                              void* d_out, int out_size, void* d_ws, size_t ws_size,
                              hipStream_t stream) {
    const float* h   = (const float*)d_in[0];
    const int*   adj = (const int*)d_in[1];
    const float* W   = (const float*)d_in[2];
    const float* a   = (const float*)d_in[3];
    float* out = (float*)d_out;
    char* ws = (char*)d_ws;

    // workspace layout (bytes)
    const size_t G_OFF  = 0;         // 8 MB reserved (bf16 path uses first 4 MB)
    const size_t EL_OFF = 8388608;   // 128 KB
    const size_t ER_OFF = 8519680;   // 128 KB
    const size_t BM_OFF = 8650752;   // 2 MB
    const size_t WHI_OFF = 10747904; // 512 KB
    const size_t WLO_OFF = 11272192; // 512 KB
    const size_t NEED_FULL = 11796480;

    float* el = (float*)(ws + EL_OFF);
    float* er = (float*)(ws + ER_OFF);

    if (ws_size >= NEED_FULL) {
        unsigned short* gbf  = (unsigned short*)(ws + G_OFF);
        unsigned short* bm   = (unsigned short*)(ws + BM_OFF);
        unsigned short* whiT = (unsigned short*)(ws + WHI_OFF);
        unsigned short* wloT = (unsigned short*)(ws + WLO_OFF);
        streampack<<<4352, 256, 0, stream>>>(adj, bm, W, whiT, wloT);
        gemm_f32A<<<512, 256, 0, stream>>>(h, (const bf16_t*)whiT, (const bf16_t*)wloT,
                                           a, gbf, el, er);
        gat_attn_wave<<<1024, 512, 0, stream>>>((const unsigned long long*)bm, gbf, el, er, out);
    } else {
        float* g = (float*)(ws + G_OFF);
        gemm_f32<<<dim3(8, 64), 256, 0, stream>>>(h, W, g);
        el_er_kernel<<<N_NODES, 512, 0, stream>>>(g, a, el, er);
        gat_attn_f32<<<N_NODES, 512, 0, stream>>>(adj, g, el, er, out);
    }
}